// Round 9
// baseline (625.655 us; speedup 1.0000x reference)
//
#include <hip/hip_runtime.h>
#include <hip/hip_bf16.h>
#include <stdint.h>

typedef unsigned short u16;
typedef unsigned int u32;

#define TSLOT 2097152              // elements per [4][8][512][128] tensor
#define XT_ELEMS 4734976ull        // 8 x 34 x 34 x 512
#define WB_ELEMS 14155776ull       // 6 x 512 x 4608 (tap-major k')
#define WPB_ELEMS 524288ull        // 2 x 512 x 512

typedef __attribute__((ext_vector_type(8))) short short8;
typedef __attribute__((ext_vector_type(8))) unsigned short u16x8;
typedef __attribute__((ext_vector_type(4))) float f32x4;

__device__ __forceinline__ u16 f2bf(float f) {
    union { u32 i; float f; } v; v.f = f;
    u32 u = v.i;
    return (u16)((u + 0x7FFFu + ((u >> 16) & 1u)) >> 16);  // RNE
}
__device__ __forceinline__ u32 pkbf(float a, float b) {
    __hip_bfloat162 h = __float22bfloat162_rn(make_float2(a, b));
    u32 u; __builtin_memcpy(&u, &h, 4); return u;
}

// async global->LDS, 16B per lane; lds dest is wave-uniform base + lane*16.
// Source address is PER-LANE ARBITRARY (only needs 16B contiguity per lane).
__device__ __forceinline__ void gl_lds16(const u16* g, u16* l) {
    __builtin_amdgcn_global_load_lds(
        (const __attribute__((address_space(1))) void*)(uintptr_t)(const void*)g,
        (__attribute__((address_space(3))) void*)(uintptr_t)(void*)l,
        16, 0, 0);
}

// ---------------------------------------------------------------------------
// prep_all: one launch, three roles (verified round 7).
//  [0,1088):    xt transpose: xt[nimg 8][yy 34][xx 34][ci 512] bf16, zero-pad
//  [1088,4160): conv-weight reorder fp32->bf16 tap-major: k' = tap*512+ci
//  [4160,4288): proj weights fp32->bf16  wpb[2][512][512]
// ---------------------------------------------------------------------------
__global__ __launch_bounds__(256) void prep_all(
    const float* __restrict__ xl, const float* __restrict__ xg,
    const float* __restrict__ w0, const float* __restrict__ w1,
    const float* __restrict__ w2, const float* __restrict__ w3,
    const float* __restrict__ w4, const float* __restrict__ w5,
    const float* __restrict__ wp1, const float* __restrict__ wp2,
    u16* __restrict__ xt, u16* __restrict__ wbf, u16* __restrict__ wpb)
{
    __shared__ u16 sh[4608];
    const int b = blockIdx.x;
    const int t = threadIdx.x;

    if (b < 1088) {
        const int nimg = b / 136;
        const int rem  = b - nimg * 136;
        const int yy   = rem >> 2;
        const int cig  = rem & 3;
        const int img  = nimg >> 2, n = nimg & 3;
        const float* srcx = (img ? xg : xl);
        u16* ob = xt + (((size_t)nimg * 34 + yy) * 34) * 512 + cig * 128;

        u16 (*xls)[132] = (u16(*)[132])sh;   // [xx 32][ci 128]
        const bool interior = (yy >= 1 && yy <= 32);
        if (interior) {
            for (int v = t; v < 4096; v += 256) {
                int ci_l = v >> 5, xx0 = v & 31;
                float vv = srcx[(((size_t)n * 512 + cig * 128 + ci_l) * 32 + (yy - 1)) * 32 + xx0];
                xls[xx0][ci_l] = f2bf(vv);
            }
            __syncthreads();
        }
        for (int v = t; v < 544; v += 256) {
            int xx = v >> 4, l16 = v & 15;
            u16x8 st;
            if (interior && xx >= 1 && xx <= 32) {
                #pragma unroll
                for (int j = 0; j < 8; ++j) st[j] = xls[xx - 1][l16 * 8 + j];
            } else {
                #pragma unroll
                for (int j = 0; j < 8; ++j) st[j] = 0;
            }
            *(u16x8*)(ob + (size_t)xx * 512 + l16 * 8) = st;
        }
        return;
    }
    if (b < 4160) {
        const int idx = b - 1088;
        const int wt = idx >> 9, co = idx & 511;
        const float* srcw = wt == 0 ? w0 : wt == 1 ? w1 : wt == 2 ? w2
                          : wt == 3 ? w3 : wt == 4 ? w4 : w5;
        const float* wr = srcw + (size_t)co * 4608;
        #pragma unroll
        for (int j = 0; j < 18; ++j)
            sh[t * 18 + j] = f2bf(wr[t * 18 + j]);   // sh[k = ci*9+tap]
        __syncthreads();
        u16* orow = wbf + ((size_t)wt * 512 + co) * 4608;
        for (int v = t; v < 4608; v += 256) {
            int tap = v >> 9, ci = v & 511;
            orow[v] = sh[ci * 9 + tap];              // k' = tap*512+ci
        }
        return;
    }
    const int b3 = b - 4160;
    const float* src = (b3 < 64) ? wp1 : wp2;
    const size_t base = (size_t)(b3 & 63) * 4096 + t * 16;
    u16* dst = wpb + ((b3 < 64) ? 0 : 262144) + base;
    const float4* s4 = (const float4*)(src + base);
    float4 f0 = s4[0], f1 = s4[1], f2 = s4[2], f3 = s4[3];
    u32 p[4];
    p[0] = pkbf(f0.x, f0.y); p[1] = pkbf(f0.z, f0.w);
    p[2] = pkbf(f1.x, f1.y); p[3] = pkbf(f1.z, f1.w);
    *(uint4*)dst = *(uint4*)p;
    p[0] = pkbf(f2.x, f2.y); p[1] = pkbf(f2.z, f2.w);
    p[2] = pkbf(f3.x, f3.y); p[3] = pkbf(f3.z, f3.w);
    *(uint4*)(dst + 8) = *(uint4*)p;
}

// ---------------------------------------------------------------------------
// Conv GEMM v11: A direct global->VGPR (L2-resident) with 1-AHEAD register
// double-buffer; B-only LDS with v7's proven 2-DEEP staging.
//  r8 post-mortem: v10's traffic model was right (FETCH 38MB, A L2-resident)
//  but it exposed latency twice: 1-deep B (vmcnt(0) on a ~500cyc-old DMA)
//  and A loads consumed same-iteration. v11 fixes both:
//  - B: 2 slots, stageB(kt+2, s) after WAR barrier; loop-top wait is
//    vmcnt(3) (B(kt+1) stays in flight) — never 0.
//  - A: loadA(kt+1) issued mid-iteration into the other register set;
//    full iteration (~2000cyc) of L2-latency cover; drained by the same
//    loop-top vmcnt(3).
//  - LDS/CU/K-tile = B reads 96KB (~1130cyc) + writes 24KB (~190)
//    < MFMA 1863cyc -> matrix pipe is the pole.
//  - lgkmcnt(0) before the WAR barrier (hidden under the A-load burst)
//    makes the slot rewrite provably safe.
//  - accumulation order per element (kt asc, ks asc) identical to v7.
// ---------------------------------------------------------------------------
__global__ __launch_bounds__(512, 2) void conv_gemm(
    const u16* __restrict__ xt, const u16* __restrict__ wbf,
    u16* __restrict__ kl, u16* __restrict__ ql, u16* __restrict__ vl,
    u16* __restrict__ kg, u16* __restrict__ qg, u16* __restrict__ vg)
{
    __shared__ __align__(16) u16 B_lds[2][12288];   // [slot][192 rows x 64]

    const int t    = threadIdx.x;        // 0..511
    const int lane = t & 63;
    const int w    = t >> 6;             // 0..7

    // 2D XCD swizzle: XCD (bid&7) -> (mt-group, nt-group) = (x>>1, x&1)
    const int bid = blockIdx.x;          // 0..255
    const int x   = bid & 7;
    const int j   = bid >> 3;            // 0..31
    const int mt  = (x >> 1) * 8 + (j >> 2);   // 0..31
    const int nt  = (x & 1) * 4 + (j & 3);     // 0..7

    const int m0   = mt * 256;
    const int nimg = m0 >> 10;           // constant per tile
    const int img  = nimg >> 2;
    const int y0   = (m0 & 1023) >> 5;
    const int n0   = nt * 192;           // absolute col in [0,1536)

    const int l8    = lane >> 3;
    const int scol8 = ((lane & 7) ^ l8) * 8;   // pre-swizzled source chunk (B)

    const u16* bgp[3];
    #pragma unroll
    for (int i = 0; i < 3; ++i) {
        const int ra = i * 64 + w * 8 + l8;
        bgp[i] = wbf + ((size_t)img * 1536 + n0 + ra) * 4608 + scol8;
    }

    const int fr  = lane & 15;
    const int qd  = lane >> 4;
    const int wm  = (w & 3) * 64;        // wave M offset (4-way, 64 rows)
    const int wn  = (w >> 2) * 96;       // wave N offset (2-way, 96 cols)
    const int cxa = fr & 7;

    // A per-lane fragment base pointers: row = wm + mi*16 + fr, k-chunk qd
    const u16* agp[4];
    #pragma unroll
    for (int mi = 0; mi < 4; ++mi) {
        const int row = wm + mi * 16 + fr;
        const int yy  = y0 + (row >> 5);
        const int xx  = row & 31;
        agp[mi] = xt + (((size_t)nimg * 34 + yy) * 34 + xx) * 512 + qd * 8;
    }

    f32x4 acc[4][6] = {};

    auto stageB = [&](int kt, int slot) {
        #pragma unroll
        for (int i = 0; i < 3; ++i)
            gl_lds16(bgp[i] + kt * 64, &B_lds[slot][i * 4096 + w * 512]);
    };
    auto loadA = [&](int kt, short8 (&af)[4][2]) {
        const int tap = kt >> 3, cb = kt & 7;
        const int ky = tap / 3, kx = tap - ky * 3;
        const int toff = (ky * 34 + kx) * 512 + cb * 64;
        #pragma unroll
        for (int mi = 0; mi < 4; ++mi)
            #pragma unroll
            for (int ks = 0; ks < 2; ++ks)
                af[mi][ks] = *(const short8*)(agp[mi] + toff + ks * 32);
    };

    short8 afE[4][2], afO[4][2];

    // prologue: A(0) in regs; B(0),B(1) staged (issue order matters for vmcnt:
    // A(0) 8 ops oldest, then B(0) 3, then B(1) 3).
    loadA(0, afE);
    stageB(0, 0);
    stageB(1, 1);

    for (int kt = 0; kt < 72; ++kt) {
        const int s = kt & 1;
        short8 (&afC)[4][2] = (kt & 1) ? afO : afE;
        short8 (&afN)[4][2] = (kt & 1) ? afE : afO;

        // drains A(kt) [issued last iter] and B(kt) [staged 2 iters ago];
        // leaves B(kt+1)'s 3 DMAs in flight across the barrier.
        asm volatile("s_waitcnt vmcnt(3)" ::: "memory");
        asm volatile("s_barrier" ::: "memory");

        // B fragments for kt from slot s
        const u16* Bb = &B_lds[s][0];
        short8 bq[6][2];
        #pragma unroll
        for (int nj = 0; nj < 6; ++nj)
            #pragma unroll
            for (int ks = 0; ks < 2; ++ks)
                bq[nj][ks] = *(const short8*)&Bb[(wn + nj * 16 + fr) * 64
                                                 + (((ks * 4 + qd) ^ cxa) * 8)];

        // A(kt+1): 8 per-lane global loads, consumed next iteration
        int ktn = kt + 1; if (ktn >= 72) ktn = 0;     // wrap = harmless dummy
        loadA(ktn, afN);

        // my bq ds_reads complete; after barrier, every wave's do -> slot s
        // rewrite below is safe.
        asm volatile("s_waitcnt lgkmcnt(0)" ::: "memory");
        asm volatile("s_barrier" ::: "memory");

        int kt2 = kt + 2; if (kt2 >= 72) kt2 -= 72;   // wrap = harmless dummy
        stageB(kt2, s);

        __builtin_amdgcn_s_setprio(1);
        #pragma unroll
        for (int ks = 0; ks < 2; ++ks)
            #pragma unroll
            for (int mi = 0; mi < 4; ++mi)
                #pragma unroll
                for (int nj = 0; nj < 6; ++nj)
                    acc[mi][nj] = __builtin_amdgcn_mfma_f32_16x16x32_bf16(
                        afC[mi][ks], bq[nj][ks], acc[mi][nj], 0, 0, 0);
        __builtin_amdgcn_s_setprio(0);
    }

    // epilogue: rows m = m0 + wm + i*16 + qd*4 + r
    //           cols (absolute) = n0 + wn + j*16 + fr  -> (wtj, co) per frag
    const int m_in = m0 & 4095;
    const int n_i  = m_in >> 10;
    const int sp0  = m_in & 1023;
    #pragma unroll
    for (int i = 0; i < 4; ++i) {
        const int mrow = wm + i * 16;
        const int head = (sp0 + mrow) >> 7;
        const int dd0  = (mrow & 127) + qd * 4;
        const size_t hoff = (size_t)(n_i * 8 + head) * 65536;
        #pragma unroll
        for (int jn = 0; jn < 6; ++jn) {
            const int co_abs = n0 + wn + jn * 16 + fr;
            const int wtj = co_abs >> 9;          // wave-uniform
            const int co  = co_abs & 511;
            u16* osel = img == 0 ? (wtj == 0 ? kl : wtj == 1 ? ql : vl)
                                 : (wtj == 0 ? kg : wtj == 1 ? qg : vg);
            u16* ob = osel + hoff;
            if (wtj == 2) {
                // V transposed: [dd][co]
                #pragma unroll
                for (int r = 0; r < 4; ++r)
                    ob[(size_t)(dd0 + r) * 512 + co] = f2bf(acc[i][jn][r]);
            } else {
                ushort4 st;
                st.x = f2bf(acc[i][jn][0]); st.y = f2bf(acc[i][jn][1]);
                st.z = f2bf(acc[i][jn][2]); st.w = f2bf(acc[i][jn][3]);
                *(ushort4*)(ob + (size_t)co * 128 + dd0) = st;
            }
        }
    }
}

// ---------------------------------------------------------------------------
// MFMA flash attention v3 + XCD-local K/V (verified round 4: ~-10.5 us):
// grid is (nh, qt, z) so the 8 q-tile blocks sharing one head's K/V land
// on one XCD (bid%8 = nh%8).
// ---------------------------------------------------------------------------
__global__ __launch_bounds__(256) void attn_mfma(
    const u16* __restrict__ Q0, const u16* __restrict__ K0,
    const u16* __restrict__ V0, u16* __restrict__ O0,
    const u16* __restrict__ Q1, const u16* __restrict__ K1,
    const u16* __restrict__ V1, u16* __restrict__ O1)
{
    __shared__ __align__(16) u16 Klo[64 * 64];
    __shared__ __align__(16) u16 Khi[64 * 64];
    __shared__ __align__(16) u16 Vs[128 * 64];
    __shared__ u16 Ps[64][72];

    const int t    = threadIdx.x;
    const int lane = t & 63;
    const int w    = t >> 6;
    const int nh   = blockIdx.x;   // head fastest -> same XCD shares K/V
    const int qt   = blockIdx.y;
    const int z    = blockIdx.z;

    const u16* Q = (z ? Q1 : Q0) + (size_t)nh * 65536;
    const u16* K = (z ? K1 : K0) + (size_t)nh * 65536;
    const u16* V = (z ? V1 : V0) + (size_t)nh * 65536;
    u16*       O = (z ? O1 : O0) + (size_t)nh * 65536;

    const int q0    = qt * 64;
    const int s_rb  = w * 8 + (lane >> 3);
    const int s_col = ((lane & 7) ^ (lane >> 3)) * 8;
    u16* const dKl = Klo + w * 512;
    u16* const dKh = Khi + w * 512;
    u16* const dV  = Vs  + w * 512;

    const int fr  = lane & 15;
    const int qd  = lane >> 4;
    const int koq = qd * 8;

    #pragma unroll
    for (int i = 0; i < 2; ++i) {
        const u16* qr = Q + (size_t)(q0 + s_rb + i * 32) * 128;
        gl_lds16(qr + s_col,      dKl + i * 2048);
        gl_lds16(qr + 64 + s_col, dKh + i * 2048);
    }
    __syncthreads();
    short8 aq[4];
    #pragma unroll
    for (int dstep = 0; dstep < 4; ++dstep) {
        const u16* Qh = (dstep < 2) ? Klo : Khi;
        const int cq = (((dstep & 1) * 4 + qd) ^ (fr & 7)) * 8;
        aq[dstep] = *(const short8*)&Qh[(w * 16 + fr) * 64 + cq];
    }

    float m_run[4] = {-3e38f, -3e38f, -3e38f, -3e38f};
    float l_run[4] = {0.f, 0.f, 0.f, 0.f};
    f32x4 Ot[8] = {};
    const float scale = 0.08838834764831845f;

    for (int cb = 0; cb < 8; ++cb) {
        __syncthreads();
        const int kb = cb * 64;
        #pragma unroll
        for (int i = 0; i < 2; ++i) {
            const u16* kr = K + (size_t)(kb + s_rb + i * 32) * 128;
            gl_lds16(kr + s_col,      dKl + i * 2048);
            gl_lds16(kr + 64 + s_col, dKh + i * 2048);
        }
        #pragma unroll
        for (int i = 0; i < 4; ++i)
            gl_lds16(V + (size_t)(s_rb + i * 32) * 512 + kb + s_col, dV + i * 2048);
        __syncthreads();

        f32x4 s[4] = {};
        #pragma unroll
        for (int dstep = 0; dstep < 4; ++dstep) {
            const u16* Kh = (dstep < 2) ? Klo : Khi;
            const int cq = (((dstep & 1) * 4 + qd) ^ (fr & 7)) * 8;
            #pragma unroll
            for (int nj = 0; nj < 4; ++nj) {
                short8 bkf = *(const short8*)&Kh[(nj * 16 + fr) * 64 + cq];
                s[nj] = __builtin_amdgcn_mfma_f32_16x16x32_bf16(aq[dstep], bkf, s[nj], 0, 0, 0);
            }
        }

        float al[4];
        #pragma unroll
        for (int r = 0; r < 4; ++r) {
            float mc = fmaxf(fmaxf(s[0][r], s[1][r]), fmaxf(s[2][r], s[3][r])) * scale;
            mc = fmaxf(mc, __shfl_xor(mc, 1));
            mc = fmaxf(mc, __shfl_xor(mc, 2));
            mc = fmaxf(mc, __shfl_xor(mc, 4));
            mc = fmaxf(mc, __shfl_xor(mc, 8));
            float mn = fmaxf(m_run[r], mc);
            al[r] = __expf(m_run[r] - mn);
            m_run[r] = mn;
            float rs = 0.f;
            #pragma unroll
            for (int nj = 0; nj < 4; ++nj) {
                float p = __expf(s[nj][r] * scale - mn);
                s[nj][r] = p;
                rs += p;
            }
            rs += __shfl_xor(rs, 1);
            rs += __shfl_xor(rs, 2);
            rs += __shfl_xor(rs, 4);
            rs += __shfl_xor(rs, 8);
            l_run[r] = l_run[r] * al[r] + rs;
        }

        #pragma unroll
        for (int nj = 0; nj < 4; ++nj)
            #pragma unroll
            for (int r = 0; r < 4; ++r)
                Ps[w * 16 + qd * 4 + r][nj * 16 + fr] = f2bf(s[nj][r]);

        {
            int srcl = (fr >> 2) << 4;
            float a0 = __shfl(al[0], srcl), a1 = __shfl(al[1], srcl);
            float a2 = __shfl(al[2], srcl), a3 = __shfl(al[3], srcl);
            int rsel = fr & 3;
            float ac = rsel == 0 ? a0 : rsel == 1 ? a1 : rsel == 2 ? a2 : a3;
            #pragma unroll
            for (int t8 = 0; t8 < 8; ++t8)
                #pragma unroll
                for (int r = 0; r < 4; ++r)
                    Ot[t8][r] *= ac;
        }

        #pragma unroll
        for (int ks = 0; ks < 2; ++ks) {
            short8 b = *(const short8*)&Ps[w * 16 + fr][ks * 32 + koq];
            #pragma unroll
            for (int t8 = 0; t8 < 8; ++t8) {
                const int cv = ((ks * 4 + qd) ^ (fr & 7)) * 8;
                short8 a = *(const short8*)&Vs[(t8 * 16 + fr) * 64 + cv];
                Ot[t8] = __builtin_amdgcn_mfma_f32_16x16x32_bf16(a, b, Ot[t8], 0, 0, 0);
            }
        }
    }

    int srcl = (fr >> 2) << 4;
    float l0 = __shfl(l_run[0], srcl), l1 = __shfl(l_run[1], srcl);
    float l2 = __shfl(l_run[2], srcl), l3 = __shfl(l_run[3], srcl);
    int rsel = fr & 3;
    float lc = rsel == 0 ? l0 : rsel == 1 ? l1 : rsel == 2 ? l2 : l3;
    float linv = 1.0f / lc;
    int c = q0 + w * 16 + fr;
    #pragma unroll
    for (int t8 = 0; t8 < 8; ++t8)
        #pragma unroll
        for (int r = 0; r < 4; ++r) {
            int d = t8 * 16 + qd * 4 + r;
            O[(size_t)d * 512 + c] = f2bf(Ot[t8][r] * linv);
        }
}

// ---------------------------------------------------------------------------
// Projection GEMM + residual (verified round 6): DMA staging, BK=64.
// ---------------------------------------------------------------------------
__global__ __launch_bounds__(256) void proj_mfma(
    const u16* __restrict__ wpb,
    const u16* __restrict__ Otl, const u16* __restrict__ Otg,
    const float* __restrict__ x_l, const float* __restrict__ x_g,
    const float* __restrict__ rwp,
    float* __restrict__ out0, float* __restrict__ out1)
{
    __shared__ __align__(16) u16 A_lds[128 * 64];
    __shared__ __align__(16) u16 B_lds[128 * 64];

    const int t  = threadIdx.x;
    const int ct = blockIdx.x;
    const int st = blockIdx.y;
    const int z  = blockIdx.z;
    const int which = z >> 2;
    const int nn    = z & 3;

    const u16*   Wp = wpb + (which ? 262144 : 0);
    const u16*   Ot = (which ? Otg : Otl) + (size_t)nn * 524288;
    const float* xr = (which ? x_g : x_l) + (size_t)nn * 524288;
    float*     outp = (which ? out1 : out0) + (size_t)nn * 524288;

    const int co0 = ct * 128, s0 = st * 128;
    const int lane = t & 63;
    const int w4   = t >> 6;

    const int s_rb  = w4 * 8 + (lane >> 3);
    const int s_col = ((lane & 7) ^ (lane >> 3)) * 8;
    const u16* agp[4];
    const u16* bgp[4];
    #pragma unroll
    for (int i = 0; i < 4; ++i) {
        agp[i] = Wp + (size_t)(co0 + s_rb + i * 32) * 512 + s_col;
        bgp[i] = Ot + (size_t)(s0  + s_rb + i * 32) * 512 + s_col;
    }
    u16* Adst = A_lds + w4 * 512;
    u16* Bdst = B_lds + w4 * 512;

    const int wm = (w4 & 1) * 64;
    const int wn = (w4 >> 1) * 64;
    const int fr = lane & 15;
    const int qd = lane >> 4;
    int arow[4], brow[4];
    #pragma unroll
    for (int i = 0; i < 4; ++i) {
        arow[i] = wm + i * 16 + fr;
        brow[i] = wn + i * 16 + fr;
    }

    f32x4 acc[4][4] = {};

    for (int kb = 0; kb < 512; kb += 64) {
        __syncthreads();
        #pragma unroll
        for (int i = 0; i < 4; ++i) {
            gl_lds16(agp[i] + kb, Adst + i * 2048);
            gl_lds16(bgp[i] + kb, Bdst + i * 2048);
        }
        __syncthreads();
        #pragma unroll
        for (int ks = 0; ks < 2; ++ks) {
            short8 af[4], bq[4];
            #pragma unroll
            for (int i = 0; i < 4; ++i) {
                int c = (ks * 4 + qd) ^ (arow[i] & 7);
                af[i] = *(const short8*)&A_lds[arow[i] * 64 + c * 8];
            }
            #pragma unroll
            for (int j = 0; j < 4; ++j) {
                int c = (ks * 4 + qd) ^ (brow[j] & 7);
                bq[j] = *(const short8*)&B_lds[brow[j] * 64 + c * 8];
            }
            #pragma unroll
            for (int i = 0; i < 4; ++i)
                #pragma unroll
                for (int j = 0; j < 4; ++j)
                    acc[i][j] = __builtin_amdgcn_mfma_f32_16x16x32_bf16(
                        af[i], bq[j], acc[i][j], 0, 0, 0);
        }
    }

    const float rwv = *rwp;
    #pragma unroll
    for (int i = 0; i < 4; ++i) {
        int co_b = co0 + wm + i * 16 + qd * 4;
        #pragma unroll
        for (int j = 0; j < 4; ++j) {
            int s = s0 + wn + j * 16 + fr;
            #pragma unroll
            for (int r = 0; r < 4; ++r) {
                size_t a = (size_t)(co_b + r) * 1024 + s;
                outp[a] = xr[a] + rwv * acc[i][j][r];
            }
        }
    }
}

// ---------------------------------------------------------------------------
extern "C" void kernel_launch(void* const* d_in, const int* in_sizes, int n_in,
                              void* d_out, int out_size, void* d_ws, size_t ws_size,
                              hipStream_t stream) {
    const float* x_l = (const float*)d_in[0];
    const float* x_g = (const float*)d_in[1];
    const float* Wk1 = (const float*)d_in[2];
    const float* Wq1 = (const float*)d_in[3];
    const float* Wv1 = (const float*)d_in[4];
    const float* Wk2 = (const float*)d_in[5];
    const float* Wq2 = (const float*)d_in[6];
    const float* Wv2 = (const float*)d_in[7];
    const float* Wp1 = (const float*)d_in[8];
    const float* Wp2 = (const float*)d_in[9];
    const float* rw  = (const float*)d_in[10];

    u16* ws  = (u16*)d_ws;
    u16* xt  = ws;                       // 9.5 MB
    u16* wbf = ws + XT_ELEMS;            // 28.3 MB
    u16* Kl  = wbf + WB_ELEMS;
    u16* Ql  = Kl  + TSLOT;
    u16* Vtl = Ql  + TSLOT;
    u16* Kg  = Vtl + TSLOT;
    u16* Qg  = Kg  + TSLOT;
    u16* Vtg = Qg  + TSLOT;
    u16* Otg = Vtg + TSLOT;
    u16* Otl = Otg + TSLOT;
    u16* wpb = Otl + TSLOT;              // 1 MB

    float* out0 = (float*)d_out;
    float* out1 = out0 + (size_t)TSLOT;

    prep_all<<<4288, 256, 0, stream>>>(
        x_l, x_g, Wk1, Wq1, Wv1, Wk2, Wq2, Wv2, Wp1, Wp2, xt, wbf, wpb);

    conv_gemm<<<256, 512, 0, stream>>>(
        xt, wbf, Kl, Ql, Vtl, Kg, Qg, Vtg);

    attn_mfma<<<dim3(32, 8, 2), 256, 0, stream>>>(
        Qg, Kl, Vtl, Otg, Ql, Kg, Vtg, Otl);

    proj_mfma<<<dim3(4, 8, 8), 256, 0, stream>>>(
        wpb, Otl, Otg, x_l, x_g, rw, out0, out1);
}

// Round 10
// 349.163 us; speedup vs baseline: 1.7919x; 1.7919x over previous
//
#include <hip/hip_runtime.h>
#include <hip/hip_bf16.h>
#include <stdint.h>

typedef unsigned short u16;
typedef unsigned int u32;

#define TSLOT 2097152              // elements per [4][8][512][128] tensor
#define XT_ELEMS 4734976ull        // 8 x 34 x 34 x 512
#define WB_ELEMS 14155776ull       // 6 x 512 x 4608 (tap-major k')
#define WPB_ELEMS 524288ull        // 2 x 512 x 512

typedef __attribute__((ext_vector_type(8))) short short8;
typedef __attribute__((ext_vector_type(8))) unsigned short u16x8;
typedef __attribute__((ext_vector_type(4))) float f32x4;

__device__ __forceinline__ u16 f2bf(float f) {
    union { u32 i; float f; } v; v.f = f;
    u32 u = v.i;
    return (u16)((u + 0x7FFFu + ((u >> 16) & 1u)) >> 16);  // RNE
}
__device__ __forceinline__ u32 pkbf(float a, float b) {
    __hip_bfloat162 h = __float22bfloat162_rn(make_float2(a, b));
    u32 u; __builtin_memcpy(&u, &h, 4); return u;
}

// async global->LDS, 16B per lane; lds dest is wave-uniform base + lane*16.
// Source address is PER-LANE ARBITRARY (only needs 16B contiguity per lane).
__device__ __forceinline__ void gl_lds16(const u16* g, u16* l) {
    __builtin_amdgcn_global_load_lds(
        (const __attribute__((address_space(1))) void*)(uintptr_t)(const void*)g,
        (__attribute__((address_space(3))) void*)(uintptr_t)(void*)l,
        16, 0, 0);
}

// ---------------------------------------------------------------------------
// prep_all: one launch, three roles (verified round 7).
//  [0,1088):    xt transpose: xt[nimg 8][yy 34][xx 34][ci 512] bf16, zero-pad
//  [1088,4160): conv-weight reorder fp32->bf16 tap-major: k' = tap*512+ci
//  [4160,4288): proj weights fp32->bf16  wpb[2][512][512]
// ---------------------------------------------------------------------------
__global__ __launch_bounds__(256) void prep_all(
    const float* __restrict__ xl, const float* __restrict__ xg,
    const float* __restrict__ w0, const float* __restrict__ w1,
    const float* __restrict__ w2, const float* __restrict__ w3,
    const float* __restrict__ w4, const float* __restrict__ w5,
    const float* __restrict__ wp1, const float* __restrict__ wp2,
    u16* __restrict__ xt, u16* __restrict__ wbf, u16* __restrict__ wpb)
{
    __shared__ u16 sh[4608];
    const int b = blockIdx.x;
    const int t = threadIdx.x;

    if (b < 1088) {
        const int nimg = b / 136;
        const int rem  = b - nimg * 136;
        const int yy   = rem >> 2;
        const int cig  = rem & 3;
        const int img  = nimg >> 2, n = nimg & 3;
        const float* srcx = (img ? xg : xl);
        u16* ob = xt + (((size_t)nimg * 34 + yy) * 34) * 512 + cig * 128;

        u16 (*xls)[132] = (u16(*)[132])sh;   // [xx 32][ci 128]
        const bool interior = (yy >= 1 && yy <= 32);
        if (interior) {
            for (int v = t; v < 4096; v += 256) {
                int ci_l = v >> 5, xx0 = v & 31;
                float vv = srcx[(((size_t)n * 512 + cig * 128 + ci_l) * 32 + (yy - 1)) * 32 + xx0];
                xls[xx0][ci_l] = f2bf(vv);
            }
            __syncthreads();
        }
        for (int v = t; v < 544; v += 256) {
            int xx = v >> 4, l16 = v & 15;
            u16x8 st;
            if (interior && xx >= 1 && xx <= 32) {
                #pragma unroll
                for (int j = 0; j < 8; ++j) st[j] = xls[xx - 1][l16 * 8 + j];
            } else {
                #pragma unroll
                for (int j = 0; j < 8; ++j) st[j] = 0;
            }
            *(u16x8*)(ob + (size_t)xx * 512 + l16 * 8) = st;
        }
        return;
    }
    if (b < 4160) {
        const int idx = b - 1088;
        const int wt = idx >> 9, co = idx & 511;
        const float* srcw = wt == 0 ? w0 : wt == 1 ? w1 : wt == 2 ? w2
                          : wt == 3 ? w3 : wt == 4 ? w4 : w5;
        const float* wr = srcw + (size_t)co * 4608;
        #pragma unroll
        for (int j = 0; j < 18; ++j)
            sh[t * 18 + j] = f2bf(wr[t * 18 + j]);   // sh[k = ci*9+tap]
        __syncthreads();
        u16* orow = wbf + ((size_t)wt * 512 + co) * 4608;
        for (int v = t; v < 4608; v += 256) {
            int tap = v >> 9, ci = v & 511;
            orow[v] = sh[ci * 9 + tap];              // k' = tap*512+ci
        }
        return;
    }
    const int b3 = b - 4160;
    const float* src = (b3 < 64) ? wp1 : wp2;
    const size_t base = (size_t)(b3 & 63) * 4096 + t * 16;
    u16* dst = wpb + ((b3 < 64) ? 0 : 262144) + base;
    const float4* s4 = (const float4*)(src + base);
    float4 f0 = s4[0], f1 = s4[1], f2 = s4[2], f3 = s4[3];
    u32 p[4];
    p[0] = pkbf(f0.x, f0.y); p[1] = pkbf(f0.z, f0.w);
    p[2] = pkbf(f1.x, f1.y); p[3] = pkbf(f1.z, f1.w);
    *(uint4*)dst = *(uint4*)p;
    p[0] = pkbf(f2.x, f2.y); p[1] = pkbf(f2.z, f2.w);
    p[2] = pkbf(f3.x, f3.y); p[3] = pkbf(f3.z, f3.w);
    *(uint4*)(dst + 8) = *(uint4*)p;
}

// ---------------------------------------------------------------------------
// Conv GEMM v12: v11's schedule with STATIC register buffers (rule #20 fix).
//  r9 post-mortem: v11's `(kt&1) ? afO : afE` runtime reference-select sent
//  both A-fragment buffers to SCRATCH (WRITE_SIZE 34MB->1.17GB, MfmaUtil
//  9.9%). The schedule itself (B 2-deep LDS, A 1-ahead reg dbuf, loop-top
//  vmcnt(3)) was verified correct on paper. v12 drives the SAME body from a
//  36-pair loop with compile-time buffer alternation (r4-proven pattern:
//  lambda ref-params, every index static).
//  - vmcnt ledger at top of iter kt: outstanding = [B(kt) 3?] A(kt) 8,
//    B(kt+1) 3 -> vmcnt(3) drains B(kt)+A(kt), leaves B(kt+1) in flight.
//  - LDS/CU/K-tile = B reads 96KB (~1130cyc) + writes 24KB (~190)
//    < MFMA 1863cyc -> matrix pipe is the pole.
//  - A direct from L2 (FETCH 38MB verified r8); accumulation order per
//    element (kt asc, ks asc) identical to v7 -> bit-identical output.
//  PRE-COMMIT: if conv >= 107us with clean counters, revert to v7 for good.
// ---------------------------------------------------------------------------
__global__ __launch_bounds__(512, 2) void conv_gemm(
    const u16* __restrict__ xt, const u16* __restrict__ wbf,
    u16* __restrict__ kl, u16* __restrict__ ql, u16* __restrict__ vl,
    u16* __restrict__ kg, u16* __restrict__ qg, u16* __restrict__ vg)
{
    __shared__ __align__(16) u16 B_lds[2][12288];   // [slot][192 rows x 64]

    const int t    = threadIdx.x;        // 0..511
    const int lane = t & 63;
    const int w    = t >> 6;             // 0..7

    // 2D XCD swizzle: XCD (bid&7) -> (mt-group, nt-group) = (x>>1, x&1)
    const int bid = blockIdx.x;          // 0..255
    const int x   = bid & 7;
    const int j   = bid >> 3;            // 0..31
    const int mt  = (x >> 1) * 8 + (j >> 2);   // 0..31
    const int nt  = (x & 1) * 4 + (j & 3);     // 0..7

    const int m0   = mt * 256;
    const int nimg = m0 >> 10;           // constant per tile
    const int img  = nimg >> 2;
    const int y0   = (m0 & 1023) >> 5;
    const int n0   = nt * 192;           // absolute col in [0,1536)

    const int l8    = lane >> 3;
    const int scol8 = ((lane & 7) ^ l8) * 8;   // pre-swizzled source chunk (B)

    const u16* bgp[3];
    #pragma unroll
    for (int i = 0; i < 3; ++i) {
        const int ra = i * 64 + w * 8 + l8;
        bgp[i] = wbf + ((size_t)img * 1536 + n0 + ra) * 4608 + scol8;
    }

    const int fr  = lane & 15;
    const int qd  = lane >> 4;
    const int wm  = (w & 3) * 64;        // wave M offset (4-way, 64 rows)
    const int wn  = (w >> 2) * 96;       // wave N offset (2-way, 96 cols)
    const int cxa = fr & 7;

    // A per-lane fragment base pointers: row = wm + mi*16 + fr, k-chunk qd
    const u16* agp[4];
    #pragma unroll
    for (int mi = 0; mi < 4; ++mi) {
        const int row = wm + mi * 16 + fr;
        const int yy  = y0 + (row >> 5);
        const int xx  = row & 31;
        agp[mi] = xt + (((size_t)nimg * 34 + yy) * 34 + xx) * 512 + qd * 8;
    }

    f32x4 acc[4][6] = {};

    auto stageB = [&](int kt, int slot) {
        #pragma unroll
        for (int i = 0; i < 3; ++i)
            gl_lds16(bgp[i] + kt * 64, &B_lds[slot][i * 4096 + w * 512]);
    };
    auto loadA = [&](int kt, short8 (&af)[4][2]) {
        const int tap = kt >> 3, cb = kt & 7;
        const int ky = tap / 3, kx = tap - ky * 3;
        const int toff = (ky * 34 + kx) * 512 + cb * 64;
        #pragma unroll
        for (int mi = 0; mi < 4; ++mi)
            #pragma unroll
            for (int ks = 0; ks < 2; ++ks)
                af[mi][ks] = *(const short8*)(agp[mi] + toff + ks * 32);
    };

    // body: compile-time afC/afN (ref params, statically alternated by the
    // 2x-unrolled pairing loop) — no runtime buffer selection anywhere.
    auto body = [&](int kt, short8 (&afC)[4][2], short8 (&afN)[4][2], int s) {
        // drains A(kt) + B(kt); leaves B(kt+1)'s 3 DMAs in flight
        asm volatile("s_waitcnt vmcnt(3)" ::: "memory");
        asm volatile("s_barrier" ::: "memory");

        const u16* Bb = &B_lds[s][0];
        short8 bq[6][2];
        #pragma unroll
        for (int nj = 0; nj < 6; ++nj)
            #pragma unroll
            for (int ks = 0; ks < 2; ++ks)
                bq[nj][ks] = *(const short8*)&Bb[(wn + nj * 16 + fr) * 64
                                                 + (((ks * 4 + qd) ^ cxa) * 8)];

        // A(kt+1): 8 per-lane L2 loads, consumed next body (full-iter cover)
        int ktn = kt + 1; if (ktn >= 72) ktn = 0;     // wrap = harmless dummy
        loadA(ktn, afN);

        // my bq ds_reads done; after barrier every wave's are -> slot-s
        // rewrite below is safe
        asm volatile("s_waitcnt lgkmcnt(0)" ::: "memory");
        asm volatile("s_barrier" ::: "memory");

        int kt2 = kt + 2; if (kt2 >= 72) kt2 -= 72;   // wrap = harmless dummy
        stageB(kt2, s);

        __builtin_amdgcn_s_setprio(1);
        #pragma unroll
        for (int ks = 0; ks < 2; ++ks)
            #pragma unroll
            for (int mi = 0; mi < 4; ++mi)
                #pragma unroll
                for (int nj = 0; nj < 6; ++nj)
                    acc[mi][nj] = __builtin_amdgcn_mfma_f32_16x16x32_bf16(
                        afC[mi][ks], bq[nj][ks], acc[mi][nj], 0, 0, 0);
        __builtin_amdgcn_s_setprio(0);
    };

    short8 afE[4][2], afO[4][2];

    // prologue: A(0) oldest, then B(0), B(1)
    loadA(0, afE);
    stageB(0, 0);
    stageB(1, 1);

    for (int kp = 0; kp < 36; ++kp) {
        body(kp * 2,     afE, afO, 0);
        body(kp * 2 + 1, afO, afE, 1);
    }

    // epilogue: rows m = m0 + wm + i*16 + qd*4 + r
    //           cols (absolute) = n0 + wn + j*16 + fr  -> (wtj, co) per frag
    const int m_in = m0 & 4095;
    const int n_i  = m_in >> 10;
    const int sp0  = m_in & 1023;
    #pragma unroll
    for (int i = 0; i < 4; ++i) {
        const int mrow = wm + i * 16;
        const int head = (sp0 + mrow) >> 7;
        const int dd0  = (mrow & 127) + qd * 4;
        const size_t hoff = (size_t)(n_i * 8 + head) * 65536;
        #pragma unroll
        for (int jn = 0; jn < 6; ++jn) {
            const int co_abs = n0 + wn + jn * 16 + fr;
            const int wtj = co_abs >> 9;          // wave-uniform
            const int co  = co_abs & 511;
            u16* osel = img == 0 ? (wtj == 0 ? kl : wtj == 1 ? ql : vl)
                                 : (wtj == 0 ? kg : wtj == 1 ? qg : vg);
            u16* ob = osel + hoff;
            if (wtj == 2) {
                // V transposed: [dd][co]
                #pragma unroll
                for (int r = 0; r < 4; ++r)
                    ob[(size_t)(dd0 + r) * 512 + co] = f2bf(acc[i][jn][r]);
            } else {
                ushort4 st;
                st.x = f2bf(acc[i][jn][0]); st.y = f2bf(acc[i][jn][1]);
                st.z = f2bf(acc[i][jn][2]); st.w = f2bf(acc[i][jn][3]);
                *(ushort4*)(ob + (size_t)co * 128 + dd0) = st;
            }
        }
    }
}

// ---------------------------------------------------------------------------
// MFMA flash attention v3 + XCD-local K/V (verified round 4: ~-10.5 us):
// grid is (nh, qt, z) so the 8 q-tile blocks sharing one head's K/V land
// on one XCD (bid%8 = nh%8).
// ---------------------------------------------------------------------------
__global__ __launch_bounds__(256) void attn_mfma(
    const u16* __restrict__ Q0, const u16* __restrict__ K0,
    const u16* __restrict__ V0, u16* __restrict__ O0,
    const u16* __restrict__ Q1, const u16* __restrict__ K1,
    const u16* __restrict__ V1, u16* __restrict__ O1)
{
    __shared__ __align__(16) u16 Klo[64 * 64];
    __shared__ __align__(16) u16 Khi[64 * 64];
    __shared__ __align__(16) u16 Vs[128 * 64];
    __shared__ u16 Ps[64][72];

    const int t    = threadIdx.x;
    const int lane = t & 63;
    const int w    = t >> 6;
    const int nh   = blockIdx.x;   // head fastest -> same XCD shares K/V
    const int qt   = blockIdx.y;
    const int z    = blockIdx.z;

    const u16* Q = (z ? Q1 : Q0) + (size_t)nh * 65536;
    const u16* K = (z ? K1 : K0) + (size_t)nh * 65536;
    const u16* V = (z ? V1 : V0) + (size_t)nh * 65536;
    u16*       O = (z ? O1 : O0) + (size_t)nh * 65536;

    const int q0    = qt * 64;
    const int s_rb  = w * 8 + (lane >> 3);
    const int s_col = ((lane & 7) ^ (lane >> 3)) * 8;
    u16* const dKl = Klo + w * 512;
    u16* const dKh = Khi + w * 512;
    u16* const dV  = Vs  + w * 512;

    const int fr  = lane & 15;
    const int qd  = lane >> 4;
    const int koq = qd * 8;

    #pragma unroll
    for (int i = 0; i < 2; ++i) {
        const u16* qr = Q + (size_t)(q0 + s_rb + i * 32) * 128;
        gl_lds16(qr + s_col,      dKl + i * 2048);
        gl_lds16(qr + 64 + s_col, dKh + i * 2048);
    }
    __syncthreads();
    short8 aq[4];
    #pragma unroll
    for (int dstep = 0; dstep < 4; ++dstep) {
        const u16* Qh = (dstep < 2) ? Klo : Khi;
        const int cq = (((dstep & 1) * 4 + qd) ^ (fr & 7)) * 8;
        aq[dstep] = *(const short8*)&Qh[(w * 16 + fr) * 64 + cq];
    }

    float m_run[4] = {-3e38f, -3e38f, -3e38f, -3e38f};
    float l_run[4] = {0.f, 0.f, 0.f, 0.f};
    f32x4 Ot[8] = {};
    const float scale = 0.08838834764831845f;

    for (int cb = 0; cb < 8; ++cb) {
        __syncthreads();
        const int kb = cb * 64;
        #pragma unroll
        for (int i = 0; i < 2; ++i) {
            const u16* kr = K + (size_t)(kb + s_rb + i * 32) * 128;
            gl_lds16(kr + s_col,      dKl + i * 2048);
            gl_lds16(kr + 64 + s_col, dKh + i * 2048);
        }
        #pragma unroll
        for (int i = 0; i < 4; ++i)
            gl_lds16(V + (size_t)(s_rb + i * 32) * 512 + kb + s_col, dV + i * 2048);
        __syncthreads();

        f32x4 s[4] = {};
        #pragma unroll
        for (int dstep = 0; dstep < 4; ++dstep) {
            const u16* Kh = (dstep < 2) ? Klo : Khi;
            const int cq = (((dstep & 1) * 4 + qd) ^ (fr & 7)) * 8;
            #pragma unroll
            for (int nj = 0; nj < 4; ++nj) {
                short8 bkf = *(const short8*)&Kh[(nj * 16 + fr) * 64 + cq];
                s[nj] = __builtin_amdgcn_mfma_f32_16x16x32_bf16(aq[dstep], bkf, s[nj], 0, 0, 0);
            }
        }

        float al[4];
        #pragma unroll
        for (int r = 0; r < 4; ++r) {
            float mc = fmaxf(fmaxf(s[0][r], s[1][r]), fmaxf(s[2][r], s[3][r])) * scale;
            mc = fmaxf(mc, __shfl_xor(mc, 1));
            mc = fmaxf(mc, __shfl_xor(mc, 2));
            mc = fmaxf(mc, __shfl_xor(mc, 4));
            mc = fmaxf(mc, __shfl_xor(mc, 8));
            float mn = fmaxf(m_run[r], mc);
            al[r] = __expf(m_run[r] - mn);
            m_run[r] = mn;
            float rs = 0.f;
            #pragma unroll
            for (int nj = 0; nj < 4; ++nj) {
                float p = __expf(s[nj][r] * scale - mn);
                s[nj][r] = p;
                rs += p;
            }
            rs += __shfl_xor(rs, 1);
            rs += __shfl_xor(rs, 2);
            rs += __shfl_xor(rs, 4);
            rs += __shfl_xor(rs, 8);
            l_run[r] = l_run[r] * al[r] + rs;
        }

        #pragma unroll
        for (int nj = 0; nj < 4; ++nj)
            #pragma unroll
            for (int r = 0; r < 4; ++r)
                Ps[w * 16 + qd * 4 + r][nj * 16 + fr] = f2bf(s[nj][r]);

        {
            int srcl = (fr >> 2) << 4;
            float a0 = __shfl(al[0], srcl), a1 = __shfl(al[1], srcl);
            float a2 = __shfl(al[2], srcl), a3 = __shfl(al[3], srcl);
            int rsel = fr & 3;
            float ac = rsel == 0 ? a0 : rsel == 1 ? a1 : rsel == 2 ? a2 : a3;
            #pragma unroll
            for (int t8 = 0; t8 < 8; ++t8)
                #pragma unroll
                for (int r = 0; r < 4; ++r)
                    Ot[t8][r] *= ac;
        }

        #pragma unroll
        for (int ks = 0; ks < 2; ++ks) {
            short8 b = *(const short8*)&Ps[w * 16 + fr][ks * 32 + koq];
            #pragma unroll
            for (int t8 = 0; t8 < 8; ++t8) {
                const int cv = ((ks * 4 + qd) ^ (fr & 7)) * 8;
                short8 a = *(const short8*)&Vs[(t8 * 16 + fr) * 64 + cv];
                Ot[t8] = __builtin_amdgcn_mfma_f32_16x16x32_bf16(a, b, Ot[t8], 0, 0, 0);
            }
        }
    }

    int srcl = (fr >> 2) << 4;
    float l0 = __shfl(l_run[0], srcl), l1 = __shfl(l_run[1], srcl);
    float l2 = __shfl(l_run[2], srcl), l3 = __shfl(l_run[3], srcl);
    int rsel = fr & 3;
    float lc = rsel == 0 ? l0 : rsel == 1 ? l1 : rsel == 2 ? l2 : l3;
    float linv = 1.0f / lc;
    int c = q0 + w * 16 + fr;
    #pragma unroll
    for (int t8 = 0; t8 < 8; ++t8)
        #pragma unroll
        for (int r = 0; r < 4; ++r) {
            int d = t8 * 16 + qd * 4 + r;
            O[(size_t)d * 512 + c] = f2bf(Ot[t8][r] * linv);
        }
}

// ---------------------------------------------------------------------------
// Projection GEMM + residual (verified round 6): DMA staging, BK=64.
// ---------------------------------------------------------------------------
__global__ __launch_bounds__(256) void proj_mfma(
    const u16* __restrict__ wpb,
    const u16* __restrict__ Otl, const u16* __restrict__ Otg,
    const float* __restrict__ x_l, const float* __restrict__ x_g,
    const float* __restrict__ rwp,
    float* __restrict__ out0, float* __restrict__ out1)
{
    __shared__ __align__(16) u16 A_lds[128 * 64];
    __shared__ __align__(16) u16 B_lds[128 * 64];

    const int t  = threadIdx.x;
    const int ct = blockIdx.x;
    const int st = blockIdx.y;
    const int z  = blockIdx.z;
    const int which = z >> 2;
    const int nn    = z & 3;

    const u16*   Wp = wpb + (which ? 262144 : 0);
    const u16*   Ot = (which ? Otg : Otl) + (size_t)nn * 524288;
    const float* xr = (which ? x_g : x_l) + (size_t)nn * 524288;
    float*     outp = (which ? out1 : out0) + (size_t)nn * 524288;

    const int co0 = ct * 128, s0 = st * 128;
    const int lane = t & 63;
    const int w4   = t >> 6;

    const int s_rb  = w4 * 8 + (lane >> 3);
    const int s_col = ((lane & 7) ^ (lane >> 3)) * 8;
    const u16* agp[4];
    const u16* bgp[4];
    #pragma unroll
    for (int i = 0; i < 4; ++i) {
        agp[i] = Wp + (size_t)(co0 + s_rb + i * 32) * 512 + s_col;
        bgp[i] = Ot + (size_t)(s0  + s_rb + i * 32) * 512 + s_col;
    }
    u16* Adst = A_lds + w4 * 512;
    u16* Bdst = B_lds + w4 * 512;

    const int wm = (w4 & 1) * 64;
    const int wn = (w4 >> 1) * 64;
    const int fr = lane & 15;
    const int qd = lane >> 4;
    int arow[4], brow[4];
    #pragma unroll
    for (int i = 0; i < 4; ++i) {
        arow[i] = wm + i * 16 + fr;
        brow[i] = wn + i * 16 + fr;
    }

    f32x4 acc[4][4] = {};

    for (int kb = 0; kb < 512; kb += 64) {
        __syncthreads();
        #pragma unroll
        for (int i = 0; i < 4; ++i) {
            gl_lds16(agp[i] + kb, Adst + i * 2048);
            gl_lds16(bgp[i] + kb, Bdst + i * 2048);
        }
        __syncthreads();
        #pragma unroll
        for (int ks = 0; ks < 2; ++ks) {
            short8 af[4], bq[4];
            #pragma unroll
            for (int i = 0; i < 4; ++i) {
                int c = (ks * 4 + qd) ^ (arow[i] & 7);
                af[i] = *(const short8*)&A_lds[arow[i] * 64 + c * 8];
            }
            #pragma unroll
            for (int j = 0; j < 4; ++j) {
                int c = (ks * 4 + qd) ^ (brow[j] & 7);
                bq[j] = *(const short8*)&B_lds[brow[j] * 64 + c * 8];
            }
            #pragma unroll
            for (int i = 0; i < 4; ++i)
                #pragma unroll
                for (int j = 0; j < 4; ++j)
                    acc[i][j] = __builtin_amdgcn_mfma_f32_16x16x32_bf16(
                        af[i], bq[j], acc[i][j], 0, 0, 0);
        }
    }

    const float rwv = *rwp;
    #pragma unroll
    for (int i = 0; i < 4; ++i) {
        int co_b = co0 + wm + i * 16 + qd * 4;
        #pragma unroll
        for (int j = 0; j < 4; ++j) {
            int s = s0 + wn + j * 16 + fr;
            #pragma unroll
            for (int r = 0; r < 4; ++r) {
                size_t a = (size_t)(co_b + r) * 1024 + s;
                outp[a] = xr[a] + rwv * acc[i][j][r];
            }
        }
    }
}

// ---------------------------------------------------------------------------
extern "C" void kernel_launch(void* const* d_in, const int* in_sizes, int n_in,
                              void* d_out, int out_size, void* d_ws, size_t ws_size,
                              hipStream_t stream) {
    const float* x_l = (const float*)d_in[0];
    const float* x_g = (const float*)d_in[1];
    const float* Wk1 = (const float*)d_in[2];
    const float* Wq1 = (const float*)d_in[3];
    const float* Wv1 = (const float*)d_in[4];
    const float* Wk2 = (const float*)d_in[5];
    const float* Wq2 = (const float*)d_in[6];
    const float* Wv2 = (const float*)d_in[7];
    const float* Wp1 = (const float*)d_in[8];
    const float* Wp2 = (const float*)d_in[9];
    const float* rw  = (const float*)d_in[10];

    u16* ws  = (u16*)d_ws;
    u16* xt  = ws;                       // 9.5 MB
    u16* wbf = ws + XT_ELEMS;            // 28.3 MB
    u16* Kl  = wbf + WB_ELEMS;
    u16* Ql  = Kl  + TSLOT;
    u16* Vtl = Ql  + TSLOT;
    u16* Kg  = Vtl + TSLOT;
    u16* Qg  = Kg  + TSLOT;
    u16* Vtg = Qg  + TSLOT;
    u16* Otg = Vtg + TSLOT;
    u16* Otl = Otg + TSLOT;
    u16* wpb = Otl + TSLOT;              // 1 MB

    float* out0 = (float*)d_out;
    float* out1 = out0 + (size_t)TSLOT;

    prep_all<<<4288, 256, 0, stream>>>(
        x_l, x_g, Wk1, Wq1, Wv1, Wk2, Wq2, Wv2, Wp1, Wp2, xt, wbf, wpb);

    conv_gemm<<<256, 512, 0, stream>>>(
        xt, wbf, Kl, Ql, Vtl, Kg, Qg, Vtg);

    attn_mfma<<<dim3(32, 8, 2), 256, 0, stream>>>(
        Qg, Kl, Vtl, Otg, Ql, Kg, Vtg, Otl);

    proj_mfma<<<dim3(4, 8, 8), 256, 0, stream>>>(
        wpb, Otl, Otg, x_l, x_g, rw, out0, out1);
}

// Round 11
// 268.363 us; speedup vs baseline: 2.3314x; 1.3011x over previous
//
#include <hip/hip_runtime.h>
#include <hip/hip_bf16.h>
#include <stdint.h>

typedef unsigned short u16;
typedef unsigned int u32;

#define TSLOT 2097152              // elements per [4][8][512][128] tensor
#define XT_ELEMS 4734976ull        // 8 x 34 x 34 x 512
#define WB_ELEMS 14155776ull       // 6 x 512 x 4608 (tap-major k')
#define WPB_ELEMS 524288ull        // 2 x 512 x 512

typedef __attribute__((ext_vector_type(8))) short short8;
typedef __attribute__((ext_vector_type(8))) unsigned short u16x8;
typedef __attribute__((ext_vector_type(4))) float f32x4;

__device__ __forceinline__ u16 f2bf(float f) {
    union { u32 i; float f; } v; v.f = f;
    u32 u = v.i;
    return (u16)((u + 0x7FFFu + ((u >> 16) & 1u)) >> 16);  // RNE
}
__device__ __forceinline__ u32 pkbf(float a, float b) {
    __hip_bfloat162 h = __float22bfloat162_rn(make_float2(a, b));
    u32 u; __builtin_memcpy(&u, &h, 4); return u;
}

// async global->LDS, 16B per lane; lds dest is wave-uniform base + lane*16.
// Source address is PER-LANE ARBITRARY (only needs 16B contiguity per lane).
__device__ __forceinline__ void gl_lds16(const u16* g, u16* l) {
    __builtin_amdgcn_global_load_lds(
        (const __attribute__((address_space(1))) void*)(uintptr_t)(const void*)g,
        (__attribute__((address_space(3))) void*)(uintptr_t)(void*)l,
        16, 0, 0);
}

// ---------------------------------------------------------------------------
// prep_all: one launch, three roles (verified round 7).
//  [0,1088):    xt transpose: xt[nimg 8][yy 34][xx 34][ci 512] bf16, zero-pad
//  [1088,4160): conv-weight reorder fp32->bf16 tap-major: k' = tap*512+ci
//  [4160,4288): proj weights fp32->bf16  wpb[2][512][512]
// ---------------------------------------------------------------------------
__global__ __launch_bounds__(256) void prep_all(
    const float* __restrict__ xl, const float* __restrict__ xg,
    const float* __restrict__ w0, const float* __restrict__ w1,
    const float* __restrict__ w2, const float* __restrict__ w3,
    const float* __restrict__ w4, const float* __restrict__ w5,
    const float* __restrict__ wp1, const float* __restrict__ wp2,
    u16* __restrict__ xt, u16* __restrict__ wbf, u16* __restrict__ wpb)
{
    __shared__ u16 sh[4608];
    const int b = blockIdx.x;
    const int t = threadIdx.x;

    if (b < 1088) {
        const int nimg = b / 136;
        const int rem  = b - nimg * 136;
        const int yy   = rem >> 2;
        const int cig  = rem & 3;
        const int img  = nimg >> 2, n = nimg & 3;
        const float* srcx = (img ? xg : xl);
        u16* ob = xt + (((size_t)nimg * 34 + yy) * 34) * 512 + cig * 128;

        u16 (*xls)[132] = (u16(*)[132])sh;   // [xx 32][ci 128]
        const bool interior = (yy >= 1 && yy <= 32);
        if (interior) {
            for (int v = t; v < 4096; v += 256) {
                int ci_l = v >> 5, xx0 = v & 31;
                float vv = srcx[(((size_t)n * 512 + cig * 128 + ci_l) * 32 + (yy - 1)) * 32 + xx0];
                xls[xx0][ci_l] = f2bf(vv);
            }
            __syncthreads();
        }
        for (int v = t; v < 544; v += 256) {
            int xx = v >> 4, l16 = v & 15;
            u16x8 st;
            if (interior && xx >= 1 && xx <= 32) {
                #pragma unroll
                for (int j = 0; j < 8; ++j) st[j] = xls[xx - 1][l16 * 8 + j];
            } else {
                #pragma unroll
                for (int j = 0; j < 8; ++j) st[j] = 0;
            }
            *(u16x8*)(ob + (size_t)xx * 512 + l16 * 8) = st;
        }
        return;
    }
    if (b < 4160) {
        const int idx = b - 1088;
        const int wt = idx >> 9, co = idx & 511;
        const float* srcw = wt == 0 ? w0 : wt == 1 ? w1 : wt == 2 ? w2
                          : wt == 3 ? w3 : wt == 4 ? w4 : w5;
        const float* wr = srcw + (size_t)co * 4608;
        #pragma unroll
        for (int j = 0; j < 18; ++j)
            sh[t * 18 + j] = f2bf(wr[t * 18 + j]);   // sh[k = ci*9+tap]
        __syncthreads();
        u16* orow = wbf + ((size_t)wt * 512 + co) * 4608;
        for (int v = t; v < 4608; v += 256) {
            int tap = v >> 9, ci = v & 511;
            orow[v] = sh[ci * 9 + tap];              // k' = tap*512+ci
        }
        return;
    }
    const int b3 = b - 4160;
    const float* src = (b3 < 64) ? wp1 : wp2;
    const size_t base = (size_t)(b3 & 63) * 4096 + t * 16;
    u16* dst = wpb + ((b3 < 64) ? 0 : 262144) + base;
    const float4* s4 = (const float4*)(src + base);
    float4 f0 = s4[0], f1 = s4[1], f2 = s4[2], f3 = s4[3];
    u32 p[4];
    p[0] = pkbf(f0.x, f0.y); p[1] = pkbf(f0.z, f0.w);
    p[2] = pkbf(f1.x, f1.y); p[3] = pkbf(f1.z, f1.w);
    *(uint4*)dst = *(uint4*)p;
    p[0] = pkbf(f2.x, f2.y); p[1] = pkbf(f2.z, f2.w);
    p[2] = pkbf(f3.x, f3.y); p[3] = pkbf(f3.z, f3.w);
    *(uint4*)(dst + 8) = *(uint4*)p;
}

// ---------------------------------------------------------------------------
// Conv GEMM v7 FINAL (verified r3/r6: 108-110 us, MfmaUtil 47, FETCH 39 MB).
// 256x192 tile, flat grid 256 with 2D XCD swizzle, 4Mx2N waves.
// PLATEAU NOTE: all attempts to beat this failed —
//  v8  reg-prefetch A:     119 us (same-phase B lgkm deps remained)
//  v9  2x 4-wave blocks:   107 us (blocks settle in-phase; no overlap)
//  v10 A direct, 1-deep B: 210 us (exposed DMA latency)
//  v11 A direct + dbuf:    481 us (runtime buffer select -> scratch)
//  v12 v11 fixed static:   197 us (per-lane scattered 16B loads bind TA)
// Do not revisit without a fundamentally different operand path.
// ---------------------------------------------------------------------------
__global__ __launch_bounds__(512, 2) void conv_gemm(
    const u16* __restrict__ xt, const u16* __restrict__ wbf,
    u16* __restrict__ kl, u16* __restrict__ ql, u16* __restrict__ vl,
    u16* __restrict__ kg, u16* __restrict__ qg, u16* __restrict__ vg)
{
    __shared__ __align__(16) u16 A_lds[2][16384];   // [slot][256 rows x 64]
    __shared__ __align__(16) u16 B_lds[2][12288];   // [slot][192 rows x 64]

    const int t    = threadIdx.x;        // 0..511
    const int lane = t & 63;
    const int w    = t >> 6;             // 0..7

    // 2D XCD swizzle: XCD (bid&7) -> (mt-group, nt-group) = (x>>1, x&1)
    const int bid = blockIdx.x;          // 0..255
    const int x   = bid & 7;
    const int j   = bid >> 3;            // 0..31
    const int mt  = (x >> 1) * 8 + (j >> 2);   // 0..31
    const int nt  = (x & 1) * 4 + (j & 3);     // 0..7

    const int m0   = mt * 256;
    const int nimg = m0 >> 10;           // constant per tile
    const int img  = nimg >> 2;
    const int y0   = (m0 & 1023) >> 5;
    const int n0   = nt * 192;           // absolute col in [0,1536)

    const int l8    = lane >> 3;
    const int scol8 = ((lane & 7) ^ l8) * 8;   // pre-swizzled source chunk

    const u16* agp[4];
    const u16* bgp[3];
    #pragma unroll
    for (int i = 0; i < 4; ++i) {
        const int ra = i * 64 + w * 8 + l8;
        const int yy = y0 + (ra >> 5);
        const int xx = ra & 31;
        agp[i] = xt + (((size_t)nimg * 34 + yy) * 34 + xx) * 512 + scol8;
    }
    #pragma unroll
    for (int i = 0; i < 3; ++i) {
        const int ra = i * 64 + w * 8 + l8;
        bgp[i] = wbf + ((size_t)img * 1536 + n0 + ra) * 4608 + scol8;
    }

    const int fr  = lane & 15;
    const int qd  = lane >> 4;
    const int wm  = (w & 3) * 64;        // wave M offset (4-way, 64 rows)
    const int wn  = (w >> 2) * 96;       // wave N offset (2-way, 96 cols)
    const int cxa = fr & 7;

    f32x4 acc[4][6] = {};

    auto stageA = [&](int kt, int slot) {
        const int tap = kt >> 3, cb = kt & 7;
        const int ky = tap / 3, kx = tap - ky * 3;
        const int toff = (ky * 34 + kx) * 512 + cb * 64;
        #pragma unroll
        for (int i = 0; i < 4; ++i)
            gl_lds16(agp[i] + toff, &A_lds[slot][i * 4096 + w * 512]);
    };
    auto stageB = [&](int kt, int slot) {
        #pragma unroll
        for (int i = 0; i < 3; ++i)
            gl_lds16(bgp[i] + kt * 64, &B_lds[slot][i * 4096 + w * 512]);
    };

    // prologue: 2 K-tiles in flight (14 loads/thread outstanding)
    stageA(0, 0); stageB(0, 0);
    stageA(1, 1); stageB(1, 1);

    for (int kt = 0; kt < 72; ++kt) {
        const int s = kt & 1;
        // kt's 7 loads landed; kt+1's 7 may stay in flight across the barrier
        asm volatile("s_waitcnt vmcnt(7)" ::: "memory");
        asm volatile("s_barrier" ::: "memory");

        const u16* Ab = &A_lds[s][0];
        const u16* Bb = &B_lds[s][0];

        // all A frags + first B half
        short8 af[4][2], bqA[3][2];
        #pragma unroll
        for (int mi = 0; mi < 4; ++mi)
            #pragma unroll
            for (int ks = 0; ks < 2; ++ks)
                af[mi][ks] = *(const short8*)&Ab[(wm + mi * 16 + fr) * 64
                                                 + (((ks * 4 + qd) ^ cxa) * 8)];
        #pragma unroll
        for (int nj = 0; nj < 3; ++nj)
            #pragma unroll
            for (int ks = 0; ks < 2; ++ks)
                bqA[nj][ks] = *(const short8*)&Bb[(wn + nj * 16 + fr) * 64
                                                  + (((ks * 4 + qd) ^ cxa) * 8)];

        // cluster 1: 4m x 3n x 2ks = 24 MFMA
        __builtin_amdgcn_s_setprio(1);
        #pragma unroll
        for (int ks = 0; ks < 2; ++ks)
            #pragma unroll
            for (int mi = 0; mi < 4; ++mi)
                #pragma unroll
                for (int nj = 0; nj < 3; ++nj)
                    acc[mi][nj] = __builtin_amdgcn_mfma_f32_16x16x32_bf16(
                        af[mi][ks], bqA[nj][ks], acc[mi][nj], 0, 0, 0);
        __builtin_amdgcn_s_setprio(0);

        // second B half (scheduled under cluster 1 by the compiler)
        short8 bqB[3][2];
        #pragma unroll
        for (int nj = 0; nj < 3; ++nj)
            #pragma unroll
            for (int ks = 0; ks < 2; ++ks)
                bqB[nj][ks] = *(const short8*)&Bb[(wn + 48 + nj * 16 + fr) * 64
                                                  + (((ks * 4 + qd) ^ cxa) * 8)];

        // all ds_reads of slot s are done in every wave past this point
        asm volatile("s_barrier" ::: "memory");

        int ktn = kt + 2; if (ktn >= 72) ktn -= 72;   // wrap = harmless dummy
        stageA(ktn, s);

        // cluster 2: 2m x 3n x 2ks = 12 MFMA
        __builtin_amdgcn_s_setprio(1);
        #pragma unroll
        for (int ks = 0; ks < 2; ++ks)
            #pragma unroll
            for (int mi = 0; mi < 2; ++mi)
                #pragma unroll
                for (int nj = 0; nj < 3; ++nj)
                    acc[mi][3 + nj] = __builtin_amdgcn_mfma_f32_16x16x32_bf16(
                        af[mi][ks], bqB[nj][ks], acc[mi][3 + nj], 0, 0, 0);
        __builtin_amdgcn_s_setprio(0);

        stageB(ktn, s);

        // cluster 3: 2m x 3n x 2ks = 12 MFMA
        __builtin_amdgcn_s_setprio(1);
        #pragma unroll
        for (int ks = 0; ks < 2; ++ks)
            #pragma unroll
            for (int mi = 2; mi < 4; ++mi)
                #pragma unroll
                for (int nj = 0; nj < 3; ++nj)
                    acc[mi][3 + nj] = __builtin_amdgcn_mfma_f32_16x16x32_bf16(
                        af[mi][ks], bqB[nj][ks], acc[mi][3 + nj], 0, 0, 0);
        __builtin_amdgcn_s_setprio(0);
    }

    // epilogue: rows m = m0 + wm + i*16 + qd*4 + r
    //           cols (absolute) = n0 + wn + j*16 + fr  -> (wtj, co) per frag
    const int m_in = m0 & 4095;
    const int n_i  = m_in >> 10;
    const int sp0  = m_in & 1023;
    #pragma unroll
    for (int i = 0; i < 4; ++i) {
        const int mrow = wm + i * 16;
        const int head = (sp0 + mrow) >> 7;
        const int dd0  = (mrow & 127) + qd * 4;
        const size_t hoff = (size_t)(n_i * 8 + head) * 65536;
        #pragma unroll
        for (int jn = 0; jn < 6; ++jn) {
            const int co_abs = n0 + wn + jn * 16 + fr;
            const int wtj = co_abs >> 9;          // wave-uniform
            const int co  = co_abs & 511;
            u16* osel = img == 0 ? (wtj == 0 ? kl : wtj == 1 ? ql : vl)
                                 : (wtj == 0 ? kg : wtj == 1 ? qg : vg);
            u16* ob = osel + hoff;
            if (wtj == 2) {
                // V transposed: [dd][co]
                #pragma unroll
                for (int r = 0; r < 4; ++r)
                    ob[(size_t)(dd0 + r) * 512 + co] = f2bf(acc[i][jn][r]);
            } else {
                ushort4 st;
                st.x = f2bf(acc[i][jn][0]); st.y = f2bf(acc[i][jn][1]);
                st.z = f2bf(acc[i][jn][2]); st.w = f2bf(acc[i][jn][3]);
                *(ushort4*)(ob + (size_t)co * 128 + dd0) = st;
            }
        }
    }
}

// ---------------------------------------------------------------------------
// MFMA flash attention v4: XCD-local K/V (r4) + DOUBLE-BUFFERED K/V staging.
//  r10 theory: the cb loop was fully serial (sync -> 8 DMA -> sync-drain ->
//  compute), exposing the whole DMA latency 8x per block. v4 uses the conv-
//  v7-proven pattern: 2 LDS slots (73 KB total, still 2 blocks/CU), issue
//  stageKV(cb+1) into the idle slot after a WAR barrier, counted vmcnt(8)
//  so each tile's DMA has a full compute iteration in flight. s_setprio
//  around QK/PV MFMA clusters (m191: +4-7% attn).
// ---------------------------------------------------------------------------
__global__ __launch_bounds__(256) void attn_mfma(
    const u16* __restrict__ Q0, const u16* __restrict__ K0,
    const u16* __restrict__ V0, u16* __restrict__ O0,
    const u16* __restrict__ Q1, const u16* __restrict__ K1,
    const u16* __restrict__ V1, u16* __restrict__ O1)
{
    __shared__ __align__(16) u16 Klo[2][64 * 64];
    __shared__ __align__(16) u16 Khi[2][64 * 64];
    __shared__ __align__(16) u16 Vs[2][128 * 64];
    __shared__ u16 Ps[64][72];

    const int t    = threadIdx.x;
    const int lane = t & 63;
    const int w    = t >> 6;
    const int nh   = blockIdx.x;   // head fastest -> same XCD shares K/V
    const int qt   = blockIdx.y;
    const int z    = blockIdx.z;

    const u16* Q = (z ? Q1 : Q0) + (size_t)nh * 65536;
    const u16* K = (z ? K1 : K0) + (size_t)nh * 65536;
    const u16* V = (z ? V1 : V0) + (size_t)nh * 65536;
    u16*       O = (z ? O1 : O0) + (size_t)nh * 65536;

    const int q0    = qt * 64;
    const int s_rb  = w * 8 + (lane >> 3);
    const int s_col = ((lane & 7) ^ (lane >> 3)) * 8;

    const int fr  = lane & 15;
    const int qd  = lane >> 4;
    const int koq = qd * 8;

    // Q staged through slot-0 K buffers, then held in registers
    #pragma unroll
    for (int i = 0; i < 2; ++i) {
        const u16* qr = Q + (size_t)(q0 + s_rb + i * 32) * 128;
        gl_lds16(qr + s_col,      &Klo[0][w * 512 + i * 2048]);
        gl_lds16(qr + 64 + s_col, &Khi[0][w * 512 + i * 2048]);
    }
    __syncthreads();
    short8 aq[4];
    #pragma unroll
    for (int dstep = 0; dstep < 4; ++dstep) {
        const u16* Qh = (dstep < 2) ? &Klo[0][0] : &Khi[0][0];
        const int cq = (((dstep & 1) * 4 + qd) ^ (fr & 7)) * 8;
        aq[dstep] = *(const short8*)&Qh[(w * 16 + fr) * 64 + cq];
    }
    // all waves have their aq registers -> slot 0 may be rewritten
    asm volatile("s_waitcnt lgkmcnt(0)" ::: "memory");
    asm volatile("s_barrier" ::: "memory");

    auto stageKV = [&](int cb, int sl) {
        const int kb = cb * 64;
        #pragma unroll
        for (int i = 0; i < 2; ++i) {
            const u16* kr = K + (size_t)(kb + s_rb + i * 32) * 128;
            gl_lds16(kr + s_col,      &Klo[sl][w * 512 + i * 2048]);
            gl_lds16(kr + 64 + s_col, &Khi[sl][w * 512 + i * 2048]);
        }
        #pragma unroll
        for (int i = 0; i < 4; ++i)
            gl_lds16(V + (size_t)(s_rb + i * 32) * 512 + kb + s_col,
                     &Vs[sl][w * 512 + i * 2048]);
    };

    stageKV(0, 0);                      // 8 loads/thread in flight

    float m_run[4] = {-3e38f, -3e38f, -3e38f, -3e38f};
    float l_run[4] = {0.f, 0.f, 0.f, 0.f};
    f32x4 Ot[8] = {};
    const float scale = 0.08838834764831845f;

    for (int cb = 0; cb < 8; ++cb) {
        const int s = cb & 1;
        // WAR: every wave finished reading slot s^1 (iter cb-1)
        asm volatile("s_waitcnt lgkmcnt(0)" ::: "memory");
        asm volatile("s_barrier" ::: "memory");
        if (cb < 7) {
            stageKV(cb + 1, s ^ 1);     // 16 outstanding: stage(cb)+stage(cb+1)
            asm volatile("s_waitcnt vmcnt(8)" ::: "memory");  // drain stage(cb)
        } else {
            asm volatile("s_waitcnt vmcnt(0)" ::: "memory");
        }
        asm volatile("s_barrier" ::: "memory");   // stage(cb) landed, all waves

        f32x4 sc[4] = {};
        __builtin_amdgcn_s_setprio(1);
        #pragma unroll
        for (int dstep = 0; dstep < 4; ++dstep) {
            const u16* Kh = (dstep < 2) ? &Klo[s][0] : &Khi[s][0];
            const int cq = (((dstep & 1) * 4 + qd) ^ (fr & 7)) * 8;
            #pragma unroll
            for (int nj = 0; nj < 4; ++nj) {
                short8 bkf = *(const short8*)&Kh[(nj * 16 + fr) * 64 + cq];
                sc[nj] = __builtin_amdgcn_mfma_f32_16x16x32_bf16(aq[dstep], bkf, sc[nj], 0, 0, 0);
            }
        }
        __builtin_amdgcn_s_setprio(0);

        float al[4];
        #pragma unroll
        for (int r = 0; r < 4; ++r) {
            float mc = fmaxf(fmaxf(sc[0][r], sc[1][r]), fmaxf(sc[2][r], sc[3][r])) * scale;
            mc = fmaxf(mc, __shfl_xor(mc, 1));
            mc = fmaxf(mc, __shfl_xor(mc, 2));
            mc = fmaxf(mc, __shfl_xor(mc, 4));
            mc = fmaxf(mc, __shfl_xor(mc, 8));
            float mn = fmaxf(m_run[r], mc);
            al[r] = __expf(m_run[r] - mn);
            m_run[r] = mn;
            float rs = 0.f;
            #pragma unroll
            for (int nj = 0; nj < 4; ++nj) {
                float p = __expf(sc[nj][r] * scale - mn);
                sc[nj][r] = p;
                rs += p;
            }
            rs += __shfl_xor(rs, 1);
            rs += __shfl_xor(rs, 2);
            rs += __shfl_xor(rs, 4);
            rs += __shfl_xor(rs, 8);
            l_run[r] = l_run[r] * al[r] + rs;
        }

        #pragma unroll
        for (int nj = 0; nj < 4; ++nj)
            #pragma unroll
            for (int r = 0; r < 4; ++r)
                Ps[w * 16 + qd * 4 + r][nj * 16 + fr] = f2bf(sc[nj][r]);

        {
            int srcl = (fr >> 2) << 4;
            float a0 = __shfl(al[0], srcl), a1 = __shfl(al[1], srcl);
            float a2 = __shfl(al[2], srcl), a3 = __shfl(al[3], srcl);
            int rsel = fr & 3;
            float ac = rsel == 0 ? a0 : rsel == 1 ? a1 : rsel == 2 ? a2 : a3;
            #pragma unroll
            for (int t8 = 0; t8 < 8; ++t8)
                #pragma unroll
                for (int r = 0; r < 4; ++r)
                    Ot[t8][r] *= ac;
        }

        __builtin_amdgcn_s_setprio(1);
        #pragma unroll
        for (int ks = 0; ks < 2; ++ks) {
            short8 b = *(const short8*)&Ps[w * 16 + fr][ks * 32 + koq];
            #pragma unroll
            for (int t8 = 0; t8 < 8; ++t8) {
                const int cv = ((ks * 4 + qd) ^ (fr & 7)) * 8;
                short8 a = *(const short8*)&Vs[s][(t8 * 16 + fr) * 64 + cv];
                Ot[t8] = __builtin_amdgcn_mfma_f32_16x16x32_bf16(a, b, Ot[t8], 0, 0, 0);
            }
        }
        __builtin_amdgcn_s_setprio(0);
    }

    int srcl = (fr >> 2) << 4;
    float l0 = __shfl(l_run[0], srcl), l1 = __shfl(l_run[1], srcl);
    float l2 = __shfl(l_run[2], srcl), l3 = __shfl(l_run[3], srcl);
    int rsel = fr & 3;
    float lc = rsel == 0 ? l0 : rsel == 1 ? l1 : rsel == 2 ? l2 : l3;
    float linv = 1.0f / lc;
    int c = q0 + w * 16 + fr;
    #pragma unroll
    for (int t8 = 0; t8 < 8; ++t8)
        #pragma unroll
        for (int r = 0; r < 4; ++r) {
            int d = t8 * 16 + qd * 4 + r;
            O[(size_t)d * 512 + c] = f2bf(Ot[t8][r] * linv);
        }
}

// ---------------------------------------------------------------------------
// Projection GEMM + residual (verified round 6): DMA staging, BK=64.
// ---------------------------------------------------------------------------
__global__ __launch_bounds__(256) void proj_mfma(
    const u16* __restrict__ wpb,
    const u16* __restrict__ Otl, const u16* __restrict__ Otg,
    const float* __restrict__ x_l, const float* __restrict__ x_g,
    const float* __restrict__ rwp,
    float* __restrict__ out0, float* __restrict__ out1)
{
    __shared__ __align__(16) u16 A_lds[128 * 64];
    __shared__ __align__(16) u16 B_lds[128 * 64];

    const int t  = threadIdx.x;
    const int ct = blockIdx.x;
    const int st = blockIdx.y;
    const int z  = blockIdx.z;
    const int which = z >> 2;
    const int nn    = z & 3;

    const u16*   Wp = wpb + (which ? 262144 : 0);
    const u16*   Ot = (which ? Otg : Otl) + (size_t)nn * 524288;
    const float* xr = (which ? x_g : x_l) + (size_t)nn * 524288;
    float*     outp = (which ? out1 : out0) + (size_t)nn * 524288;

    const int co0 = ct * 128, s0 = st * 128;
    const int lane = t & 63;
    const int w4   = t >> 6;

    const int s_rb  = w4 * 8 + (lane >> 3);
    const int s_col = ((lane & 7) ^ (lane >> 3)) * 8;
    const u16* agp[4];
    const u16* bgp[4];
    #pragma unroll
    for (int i = 0; i < 4; ++i) {
        agp[i] = Wp + (size_t)(co0 + s_rb + i * 32) * 512 + s_col;
        bgp[i] = Ot + (size_t)(s0  + s_rb + i * 32) * 512 + s_col;
    }
    u16* Adst = A_lds + w4 * 512;
    u16* Bdst = B_lds + w4 * 512;

    const int wm = (w4 & 1) * 64;
    const int wn = (w4 >> 1) * 64;
    const int fr = lane & 15;
    const int qd = lane >> 4;
    int arow[4], brow[4];
    #pragma unroll
    for (int i = 0; i < 4; ++i) {
        arow[i] = wm + i * 16 + fr;
        brow[i] = wn + i * 16 + fr;
    }

    f32x4 acc[4][4] = {};

    for (int kb = 0; kb < 512; kb += 64) {
        __syncthreads();
        #pragma unroll
        for (int i = 0; i < 4; ++i) {
            gl_lds16(agp[i] + kb, Adst + i * 2048);
            gl_lds16(bgp[i] + kb, Bdst + i * 2048);
        }
        __syncthreads();
        #pragma unroll
        for (int ks = 0; ks < 2; ++ks) {
            short8 af[4], bq[4];
            #pragma unroll
            for (int i = 0; i < 4; ++i) {
                int c = (ks * 4 + qd) ^ (arow[i] & 7);
                af[i] = *(const short8*)&A_lds[arow[i] * 64 + c * 8];
            }
            #pragma unroll
            for (int j = 0; j < 4; ++j) {
                int c = (ks * 4 + qd) ^ (brow[j] & 7);
                bq[j] = *(const short8*)&B_lds[brow[j] * 64 + c * 8];
            }
            #pragma unroll
            for (int i = 0; i < 4; ++i)
                #pragma unroll
                for (int j = 0; j < 4; ++j)
                    acc[i][j] = __builtin_amdgcn_mfma_f32_16x16x32_bf16(
                        af[i], bq[j], acc[i][j], 0, 0, 0);
        }
    }

    const float rwv = *rwp;
    #pragma unroll
    for (int i = 0; i < 4; ++i) {
        int co_b = co0 + wm + i * 16 + qd * 4;
        #pragma unroll
        for (int j = 0; j < 4; ++j) {
            int s = s0 + wn + j * 16 + fr;
            #pragma unroll
            for (int r = 0; r < 4; ++r) {
                size_t a = (size_t)(co_b + r) * 1024 + s;
                outp[a] = xr[a] + rwv * acc[i][j][r];
            }
        }
    }
}

// ---------------------------------------------------------------------------
extern "C" void kernel_launch(void* const* d_in, const int* in_sizes, int n_in,
                              void* d_out, int out_size, void* d_ws, size_t ws_size,
                              hipStream_t stream) {
    const float* x_l = (const float*)d_in[0];
    const float* x_g = (const float*)d_in[1];
    const float* Wk1 = (const float*)d_in[2];
    const float* Wq1 = (const float*)d_in[3];
    const float* Wv1 = (const float*)d_in[4];
    const float* Wk2 = (const float*)d_in[5];
    const float* Wq2 = (const float*)d_in[6];
    const float* Wv2 = (const float*)d_in[7];
    const float* Wp1 = (const float*)d_in[8];
    const float* Wp2 = (const float*)d_in[9];
    const float* rw  = (const float*)d_in[10];

    u16* ws  = (u16*)d_ws;
    u16* xt  = ws;                       // 9.5 MB
    u16* wbf = ws + XT_ELEMS;            // 28.3 MB
    u16* Kl  = wbf + WB_ELEMS;
    u16* Ql  = Kl  + TSLOT;
    u16* Vtl = Ql  + TSLOT;
    u16* Kg  = Vtl + TSLOT;
    u16* Qg  = Kg  + TSLOT;
    u16* Vtg = Qg  + TSLOT;
    u16* Otg = Vtg + TSLOT;
    u16* Otl = Otg + TSLOT;
    u16* wpb = Otl + TSLOT;              // 1 MB

    float* out0 = (float*)d_out;
    float* out1 = out0 + (size_t)TSLOT;

    prep_all<<<4288, 256, 0, stream>>>(
        x_l, x_g, Wk1, Wq1, Wv1, Wk2, Wq2, Wv2, Wp1, Wp2, xt, wbf, wpb);

    conv_gemm<<<256, 512, 0, stream>>>(
        xt, wbf, Kl, Ql, Vtl, Kg, Qg, Vtg);

    attn_mfma<<<dim3(32, 8, 2), 256, 0, stream>>>(
        Qg, Kl, Vtl, Otg, Ql, Kg, Vtg, Otl);

    proj_mfma<<<dim3(4, 8, 8), 256, 0, stream>>>(
        wpb, Otl, Otg, x_l, x_g, rw, out0, out1);
}

// Round 12
// 261.770 us; speedup vs baseline: 2.3901x; 1.0252x over previous
//
#include <hip/hip_runtime.h>
#include <hip/hip_bf16.h>
#include <stdint.h>

typedef unsigned short u16;
typedef unsigned int u32;

#define TSLOT 2097152              // elements per [4][8][512][128] tensor
#define XT_ELEMS 4734976ull        // 8 x 34 x 34 x 512
#define WB_ELEMS 14155776ull       // 6 x 512 x 4608 (tap-major k')
#define WPB_ELEMS 524288ull        // 2 x 512 x 512

typedef __attribute__((ext_vector_type(8))) short short8;
typedef __attribute__((ext_vector_type(8))) unsigned short u16x8;
typedef __attribute__((ext_vector_type(4))) float f32x4;

__device__ __forceinline__ u16 f2bf(float f) {
    union { u32 i; float f; } v; v.f = f;
    u32 u = v.i;
    return (u16)((u + 0x7FFFu + ((u >> 16) & 1u)) >> 16);  // RNE
}
__device__ __forceinline__ u32 pkbf(float a, float b) {
    __hip_bfloat162 h = __float22bfloat162_rn(make_float2(a, b));
    u32 u; __builtin_memcpy(&u, &h, 4); return u;
}

// async global->LDS, 16B per lane; lds dest is wave-uniform base + lane*16.
// Source address is PER-LANE ARBITRARY (only needs 16B contiguity per lane).
__device__ __forceinline__ void gl_lds16(const u16* g, u16* l) {
    __builtin_amdgcn_global_load_lds(
        (const __attribute__((address_space(1))) void*)(uintptr_t)(const void*)g,
        (__attribute__((address_space(3))) void*)(uintptr_t)(void*)l,
        16, 0, 0);
}

// ---------------------------------------------------------------------------
// prep_all: one launch, three roles.
//  [0,1088):    xt transpose: xt[nimg 8][yy 34][xx 34][ci 512] bf16, zero-pad
//  [1088,4160): conv-weight reorder fp32->bf16 tap-major: k' = tap*512+ci
//               (r12: coalesced k-loop read — wr[t*18+j] was 72B-strided)
//  [4160,4288): proj weights fp32->bf16  wpb[2][512][512]
// ---------------------------------------------------------------------------
__global__ __launch_bounds__(256) void prep_all(
    const float* __restrict__ xl, const float* __restrict__ xg,
    const float* __restrict__ w0, const float* __restrict__ w1,
    const float* __restrict__ w2, const float* __restrict__ w3,
    const float* __restrict__ w4, const float* __restrict__ w5,
    const float* __restrict__ wp1, const float* __restrict__ wp2,
    u16* __restrict__ xt, u16* __restrict__ wbf, u16* __restrict__ wpb)
{
    __shared__ u16 sh[4608];
    const int b = blockIdx.x;
    const int t = threadIdx.x;

    if (b < 1088) {
        const int nimg = b / 136;
        const int rem  = b - nimg * 136;
        const int yy   = rem >> 2;
        const int cig  = rem & 3;
        const int img  = nimg >> 2, n = nimg & 3;
        const float* srcx = (img ? xg : xl);
        u16* ob = xt + (((size_t)nimg * 34 + yy) * 34) * 512 + cig * 128;

        u16 (*xls)[132] = (u16(*)[132])sh;   // [xx 32][ci 128]
        const bool interior = (yy >= 1 && yy <= 32);
        if (interior) {
            for (int v = t; v < 4096; v += 256) {
                int ci_l = v >> 5, xx0 = v & 31;
                float vv = srcx[(((size_t)n * 512 + cig * 128 + ci_l) * 32 + (yy - 1)) * 32 + xx0];
                xls[xx0][ci_l] = f2bf(vv);
            }
            __syncthreads();
        }
        for (int v = t; v < 544; v += 256) {
            int xx = v >> 4, l16 = v & 15;
            u16x8 st;
            if (interior && xx >= 1 && xx <= 32) {
                #pragma unroll
                for (int j = 0; j < 8; ++j) st[j] = xls[xx - 1][l16 * 8 + j];
            } else {
                #pragma unroll
                for (int j = 0; j < 8; ++j) st[j] = 0;
            }
            *(u16x8*)(ob + (size_t)xx * 512 + l16 * 8) = st;
        }
        return;
    }
    if (b < 4160) {
        const int idx = b - 1088;
        const int wt = idx >> 9, co = idx & 511;
        const float* srcw = wt == 0 ? w0 : wt == 1 ? w1 : wt == 2 ? w2
                          : wt == 3 ? w3 : wt == 4 ? w4 : w5;
        const float* wr = srcw + (size_t)co * 4608;
        // identity copy fp32->bf16 into LDS: coalesced (256 consecutive
        // floats per wave-iteration) instead of the old 72B-stride pattern
        for (int k = t; k < 4608; k += 256)
            sh[k] = f2bf(wr[k]);                 // sh[k = ci*9+tap]
        __syncthreads();
        u16* orow = wbf + ((size_t)wt * 512 + co) * 4608;
        for (int v = t; v < 4608; v += 256) {
            int tap = v >> 9, ci = v & 511;
            orow[v] = sh[ci * 9 + tap];              // k' = tap*512+ci
        }
        return;
    }
    const int b3 = b - 4160;
    const float* src = (b3 < 64) ? wp1 : wp2;
    const size_t base = (size_t)(b3 & 63) * 4096 + t * 16;
    u16* dst = wpb + ((b3 < 64) ? 0 : 262144) + base;
    const float4* s4 = (const float4*)(src + base);
    float4 f0 = s4[0], f1 = s4[1], f2 = s4[2], f3 = s4[3];
    u32 p[4];
    p[0] = pkbf(f0.x, f0.y); p[1] = pkbf(f0.z, f0.w);
    p[2] = pkbf(f1.x, f1.y); p[3] = pkbf(f1.z, f1.w);
    *(uint4*)dst = *(uint4*)p;
    p[0] = pkbf(f2.x, f2.y); p[1] = pkbf(f2.z, f2.w);
    p[2] = pkbf(f3.x, f3.y); p[3] = pkbf(f3.z, f3.w);
    *(uint4*)(dst + 8) = *(uint4*)p;
}

// ---------------------------------------------------------------------------
// Conv GEMM v7 FINAL (verified r3/r6/r11: 108-110 us, MfmaUtil 46-48).
// 256x192 tile, flat grid 256 with 2D XCD swizzle, 4Mx2N waves.
// PLATEAU NOTE: v8 119us, v9 107us, v10 210us, v11 481us, v12 197us —
// do not revisit without a fundamentally different operand path.
// ---------------------------------------------------------------------------
__global__ __launch_bounds__(512, 2) void conv_gemm(
    const u16* __restrict__ xt, const u16* __restrict__ wbf,
    u16* __restrict__ kl, u16* __restrict__ ql, u16* __restrict__ vl,
    u16* __restrict__ kg, u16* __restrict__ qg, u16* __restrict__ vg)
{
    __shared__ __align__(16) u16 A_lds[2][16384];   // [slot][256 rows x 64]
    __shared__ __align__(16) u16 B_lds[2][12288];   // [slot][192 rows x 64]

    const int t    = threadIdx.x;        // 0..511
    const int lane = t & 63;
    const int w    = t >> 6;             // 0..7

    // 2D XCD swizzle: XCD (bid&7) -> (mt-group, nt-group) = (x>>1, x&1)
    const int bid = blockIdx.x;          // 0..255
    const int x   = bid & 7;
    const int j   = bid >> 3;            // 0..31
    const int mt  = (x >> 1) * 8 + (j >> 2);   // 0..31
    const int nt  = (x & 1) * 4 + (j & 3);     // 0..7

    const int m0   = mt * 256;
    const int nimg = m0 >> 10;           // constant per tile
    const int img  = nimg >> 2;
    const int y0   = (m0 & 1023) >> 5;
    const int n0   = nt * 192;           // absolute col in [0,1536)

    const int l8    = lane >> 3;
    const int scol8 = ((lane & 7) ^ l8) * 8;   // pre-swizzled source chunk

    const u16* agp[4];
    const u16* bgp[3];
    #pragma unroll
    for (int i = 0; i < 4; ++i) {
        const int ra = i * 64 + w * 8 + l8;
        const int yy = y0 + (ra >> 5);
        const int xx = ra & 31;
        agp[i] = xt + (((size_t)nimg * 34 + yy) * 34 + xx) * 512 + scol8;
    }
    #pragma unroll
    for (int i = 0; i < 3; ++i) {
        const int ra = i * 64 + w * 8 + l8;
        bgp[i] = wbf + ((size_t)img * 1536 + n0 + ra) * 4608 + scol8;
    }

    const int fr  = lane & 15;
    const int qd  = lane >> 4;
    const int wm  = (w & 3) * 64;        // wave M offset (4-way, 64 rows)
    const int wn  = (w >> 2) * 96;       // wave N offset (2-way, 96 cols)
    const int cxa = fr & 7;

    f32x4 acc[4][6] = {};

    auto stageA = [&](int kt, int slot) {
        const int tap = kt >> 3, cb = kt & 7;
        const int ky = tap / 3, kx = tap - ky * 3;
        const int toff = (ky * 34 + kx) * 512 + cb * 64;
        #pragma unroll
        for (int i = 0; i < 4; ++i)
            gl_lds16(agp[i] + toff, &A_lds[slot][i * 4096 + w * 512]);
    };
    auto stageB = [&](int kt, int slot) {
        #pragma unroll
        for (int i = 0; i < 3; ++i)
            gl_lds16(bgp[i] + kt * 64, &B_lds[slot][i * 4096 + w * 512]);
    };

    // prologue: 2 K-tiles in flight (14 loads/thread outstanding)
    stageA(0, 0); stageB(0, 0);
    stageA(1, 1); stageB(1, 1);

    for (int kt = 0; kt < 72; ++kt) {
        const int s = kt & 1;
        // kt's 7 loads landed; kt+1's 7 may stay in flight across the barrier
        asm volatile("s_waitcnt vmcnt(7)" ::: "memory");
        asm volatile("s_barrier" ::: "memory");

        const u16* Ab = &A_lds[s][0];
        const u16* Bb = &B_lds[s][0];

        // all A frags + first B half
        short8 af[4][2], bqA[3][2];
        #pragma unroll
        for (int mi = 0; mi < 4; ++mi)
            #pragma unroll
            for (int ks = 0; ks < 2; ++ks)
                af[mi][ks] = *(const short8*)&Ab[(wm + mi * 16 + fr) * 64
                                                 + (((ks * 4 + qd) ^ cxa) * 8)];
        #pragma unroll
        for (int nj = 0; nj < 3; ++nj)
            #pragma unroll
            for (int ks = 0; ks < 2; ++ks)
                bqA[nj][ks] = *(const short8*)&Bb[(wn + nj * 16 + fr) * 64
                                                  + (((ks * 4 + qd) ^ cxa) * 8)];

        // cluster 1: 4m x 3n x 2ks = 24 MFMA
        __builtin_amdgcn_s_setprio(1);
        #pragma unroll
        for (int ks = 0; ks < 2; ++ks)
            #pragma unroll
            for (int mi = 0; mi < 4; ++mi)
                #pragma unroll
                for (int nj = 0; nj < 3; ++nj)
                    acc[mi][nj] = __builtin_amdgcn_mfma_f32_16x16x32_bf16(
                        af[mi][ks], bqA[nj][ks], acc[mi][nj], 0, 0, 0);
        __builtin_amdgcn_s_setprio(0);

        // second B half (scheduled under cluster 1 by the compiler)
        short8 bqB[3][2];
        #pragma unroll
        for (int nj = 0; nj < 3; ++nj)
            #pragma unroll
            for (int ks = 0; ks < 2; ++ks)
                bqB[nj][ks] = *(const short8*)&Bb[(wn + 48 + nj * 16 + fr) * 64
                                                  + (((ks * 4 + qd) ^ cxa) * 8)];

        // all ds_reads of slot s are done in every wave past this point
        asm volatile("s_barrier" ::: "memory");

        int ktn = kt + 2; if (ktn >= 72) ktn -= 72;   // wrap = harmless dummy
        stageA(ktn, s);

        // cluster 2: 2m x 3n x 2ks = 12 MFMA
        __builtin_amdgcn_s_setprio(1);
        #pragma unroll
        for (int ks = 0; ks < 2; ++ks)
            #pragma unroll
            for (int mi = 0; mi < 2; ++mi)
                #pragma unroll
                for (int nj = 0; nj < 3; ++nj)
                    acc[mi][3 + nj] = __builtin_amdgcn_mfma_f32_16x16x32_bf16(
                        af[mi][ks], bqB[nj][ks], acc[mi][3 + nj], 0, 0, 0);
        __builtin_amdgcn_s_setprio(0);

        stageB(ktn, s);

        // cluster 3: 2m x 3n x 2ks = 12 MFMA
        __builtin_amdgcn_s_setprio(1);
        #pragma unroll
        for (int ks = 0; ks < 2; ++ks)
            #pragma unroll
            for (int mi = 2; mi < 4; ++mi)
                #pragma unroll
                for (int nj = 0; nj < 3; ++nj)
                    acc[mi][3 + nj] = __builtin_amdgcn_mfma_f32_16x16x32_bf16(
                        af[mi][ks], bqB[nj][ks], acc[mi][3 + nj], 0, 0, 0);
        __builtin_amdgcn_s_setprio(0);
    }

    // epilogue: rows m = m0 + wm + i*16 + qd*4 + r
    //           cols (absolute) = n0 + wn + j*16 + fr  -> (wtj, co) per frag
    const int m_in = m0 & 4095;
    const int n_i  = m_in >> 10;
    const int sp0  = m_in & 1023;
    #pragma unroll
    for (int i = 0; i < 4; ++i) {
        const int mrow = wm + i * 16;
        const int head = (sp0 + mrow) >> 7;
        const int dd0  = (mrow & 127) + qd * 4;
        const size_t hoff = (size_t)(n_i * 8 + head) * 65536;
        #pragma unroll
        for (int jn = 0; jn < 6; ++jn) {
            const int co_abs = n0 + wn + jn * 16 + fr;
            const int wtj = co_abs >> 9;          // wave-uniform
            const int co  = co_abs & 511;
            u16* osel = img == 0 ? (wtj == 0 ? kl : wtj == 1 ? ql : vl)
                                 : (wtj == 0 ? kg : wtj == 1 ? qg : vg);
            u16* ob = osel + hoff;
            if (wtj == 2) {
                // V transposed: [dd][co]
                #pragma unroll
                for (int r = 0; r < 4; ++r)
                    ob[(size_t)(dd0 + r) * 512 + co] = f2bf(acc[i][jn][r]);
            } else {
                ushort4 st;
                st.x = f2bf(acc[i][jn][0]); st.y = f2bf(acc[i][jn][1]);
                st.z = f2bf(acc[i][jn][2]); st.w = f2bf(acc[i][jn][3]);
                *(ushort4*)(ob + (size_t)co * 128 + dd0) = st;
            }
        }
    }
}

// ---------------------------------------------------------------------------
// MFMA flash attention v3 + XCD-local K/V (verified r6: total 261.7).
// grid is (nh, qt, z) so the 8 q-tile blocks sharing one head's K/V land
// on one XCD (bid%8 = nh%8).
// r11 NOTE: double-buffered K/V staging REGRESSED (+7us total) — K/V is
// L2-resident per-XCD; the extra WAR lgkm-barriers cost more than the DMA
// latency they hid. Keep the simple serial staging.
// ---------------------------------------------------------------------------
__global__ __launch_bounds__(256) void attn_mfma(
    const u16* __restrict__ Q0, const u16* __restrict__ K0,
    const u16* __restrict__ V0, u16* __restrict__ O0,
    const u16* __restrict__ Q1, const u16* __restrict__ K1,
    const u16* __restrict__ V1, u16* __restrict__ O1)
{
    __shared__ __align__(16) u16 Klo[64 * 64];
    __shared__ __align__(16) u16 Khi[64 * 64];
    __shared__ __align__(16) u16 Vs[128 * 64];
    __shared__ u16 Ps[64][72];

    const int t    = threadIdx.x;
    const int lane = t & 63;
    const int w    = t >> 6;
    const int nh   = blockIdx.x;   // head fastest -> same XCD shares K/V
    const int qt   = blockIdx.y;
    const int z    = blockIdx.z;

    const u16* Q = (z ? Q1 : Q0) + (size_t)nh * 65536;
    const u16* K = (z ? K1 : K0) + (size_t)nh * 65536;
    const u16* V = (z ? V1 : V0) + (size_t)nh * 65536;
    u16*       O = (z ? O1 : O0) + (size_t)nh * 65536;

    const int q0    = qt * 64;
    const int s_rb  = w * 8 + (lane >> 3);
    const int s_col = ((lane & 7) ^ (lane >> 3)) * 8;
    u16* const dKl = Klo + w * 512;
    u16* const dKh = Khi + w * 512;
    u16* const dV  = Vs  + w * 512;

    const int fr  = lane & 15;
    const int qd  = lane >> 4;
    const int koq = qd * 8;

    #pragma unroll
    for (int i = 0; i < 2; ++i) {
        const u16* qr = Q + (size_t)(q0 + s_rb + i * 32) * 128;
        gl_lds16(qr + s_col,      dKl + i * 2048);
        gl_lds16(qr + 64 + s_col, dKh + i * 2048);
    }
    __syncthreads();
    short8 aq[4];
    #pragma unroll
    for (int dstep = 0; dstep < 4; ++dstep) {
        const u16* Qh = (dstep < 2) ? Klo : Khi;
        const int cq = (((dstep & 1) * 4 + qd) ^ (fr & 7)) * 8;
        aq[dstep] = *(const short8*)&Qh[(w * 16 + fr) * 64 + cq];
    }

    float m_run[4] = {-3e38f, -3e38f, -3e38f, -3e38f};
    float l_run[4] = {0.f, 0.f, 0.f, 0.f};
    f32x4 Ot[8] = {};
    const float scale = 0.08838834764831845f;

    for (int cb = 0; cb < 8; ++cb) {
        __syncthreads();
        const int kb = cb * 64;
        #pragma unroll
        for (int i = 0; i < 2; ++i) {
            const u16* kr = K + (size_t)(kb + s_rb + i * 32) * 128;
            gl_lds16(kr + s_col,      dKl + i * 2048);
            gl_lds16(kr + 64 + s_col, dKh + i * 2048);
        }
        #pragma unroll
        for (int i = 0; i < 4; ++i)
            gl_lds16(V + (size_t)(s_rb + i * 32) * 512 + kb + s_col, dV + i * 2048);
        __syncthreads();

        f32x4 s[4] = {};
        #pragma unroll
        for (int dstep = 0; dstep < 4; ++dstep) {
            const u16* Kh = (dstep < 2) ? Klo : Khi;
            const int cq = (((dstep & 1) * 4 + qd) ^ (fr & 7)) * 8;
            #pragma unroll
            for (int nj = 0; nj < 4; ++nj) {
                short8 bkf = *(const short8*)&Kh[(nj * 16 + fr) * 64 + cq];
                s[nj] = __builtin_amdgcn_mfma_f32_16x16x32_bf16(aq[dstep], bkf, s[nj], 0, 0, 0);
            }
        }

        float al[4];
        #pragma unroll
        for (int r = 0; r < 4; ++r) {
            float mc = fmaxf(fmaxf(s[0][r], s[1][r]), fmaxf(s[2][r], s[3][r])) * scale;
            mc = fmaxf(mc, __shfl_xor(mc, 1));
            mc = fmaxf(mc, __shfl_xor(mc, 2));
            mc = fmaxf(mc, __shfl_xor(mc, 4));
            mc = fmaxf(mc, __shfl_xor(mc, 8));
            float mn = fmaxf(m_run[r], mc);
            al[r] = __expf(m_run[r] - mn);
            m_run[r] = mn;
            float rs = 0.f;
            #pragma unroll
            for (int nj = 0; nj < 4; ++nj) {
                float p = __expf(s[nj][r] * scale - mn);
                s[nj][r] = p;
                rs += p;
            }
            rs += __shfl_xor(rs, 1);
            rs += __shfl_xor(rs, 2);
            rs += __shfl_xor(rs, 4);
            rs += __shfl_xor(rs, 8);
            l_run[r] = l_run[r] * al[r] + rs;
        }

        #pragma unroll
        for (int nj = 0; nj < 4; ++nj)
            #pragma unroll
            for (int r = 0; r < 4; ++r)
                Ps[w * 16 + qd * 4 + r][nj * 16 + fr] = f2bf(s[nj][r]);

        {
            int srcl = (fr >> 2) << 4;
            float a0 = __shfl(al[0], srcl), a1 = __shfl(al[1], srcl);
            float a2 = __shfl(al[2], srcl), a3 = __shfl(al[3], srcl);
            int rsel = fr & 3;
            float ac = rsel == 0 ? a0 : rsel == 1 ? a1 : rsel == 2 ? a2 : a3;
            #pragma unroll
            for (int t8 = 0; t8 < 8; ++t8)
                #pragma unroll
                for (int r = 0; r < 4; ++r)
                    Ot[t8][r] *= ac;
        }

        #pragma unroll
        for (int ks = 0; ks < 2; ++ks) {
            short8 b = *(const short8*)&Ps[w * 16 + fr][ks * 32 + koq];
            #pragma unroll
            for (int t8 = 0; t8 < 8; ++t8) {
                const int cv = ((ks * 4 + qd) ^ (fr & 7)) * 8;
                short8 a = *(const short8*)&Vs[(t8 * 16 + fr) * 64 + cv];
                Ot[t8] = __builtin_amdgcn_mfma_f32_16x16x32_bf16(a, b, Ot[t8], 0, 0, 0);
            }
        }
    }

    int srcl = (fr >> 2) << 4;
    float l0 = __shfl(l_run[0], srcl), l1 = __shfl(l_run[1], srcl);
    float l2 = __shfl(l_run[2], srcl), l3 = __shfl(l_run[3], srcl);
    int rsel = fr & 3;
    float lc = rsel == 0 ? l0 : rsel == 1 ? l1 : rsel == 2 ? l2 : l3;
    float linv = 1.0f / lc;
    int c = q0 + w * 16 + fr;
    #pragma unroll
    for (int t8 = 0; t8 < 8; ++t8)
        #pragma unroll
        for (int r = 0; r < 4; ++r) {
            int d = t8 * 16 + qd * 4 + r;
            O[(size_t)d * 512 + c] = f2bf(Ot[t8][r] * linv);
        }
}

// ---------------------------------------------------------------------------
// Projection GEMM + residual v2: 2-deep counted-vmcnt pipeline (v7 pattern).
//  proj runs 256 blocks = 1/CU with only 4 waves: the old serial
//  sync->DMA->sync-drain->compute loop exposed full DMA latency 8x.
//  Now: A/B double-buffered (64 KB LDS, fine at 1 block/CU), loop-top
//  vmcnt(8) (counted, never 0), stage(it+2) after lgkm-drained WAR barrier.
//  Accumulation order per element (kb asc, ks asc) unchanged.
// ---------------------------------------------------------------------------
__global__ __launch_bounds__(256) void proj_mfma(
    const u16* __restrict__ wpb,
    const u16* __restrict__ Otl, const u16* __restrict__ Otg,
    const float* __restrict__ x_l, const float* __restrict__ x_g,
    const float* __restrict__ rwp,
    float* __restrict__ out0, float* __restrict__ out1)
{
    __shared__ __align__(16) u16 A_lds[2][128 * 64];
    __shared__ __align__(16) u16 B_lds[2][128 * 64];

    const int t  = threadIdx.x;
    const int ct = blockIdx.x;
    const int st = blockIdx.y;
    const int z  = blockIdx.z;
    const int which = z >> 2;
    const int nn    = z & 3;

    const u16*   Wp = wpb + (which ? 262144 : 0);
    const u16*   Ot = (which ? Otg : Otl) + (size_t)nn * 524288;
    const float* xr = (which ? x_g : x_l) + (size_t)nn * 524288;
    float*     outp = (which ? out1 : out0) + (size_t)nn * 524288;

    const int co0 = ct * 128, s0 = st * 128;
    const int lane = t & 63;
    const int w4   = t >> 6;

    const int s_rb  = w4 * 8 + (lane >> 3);
    const int s_col = ((lane & 7) ^ (lane >> 3)) * 8;
    const u16* agp[4];
    const u16* bgp[4];
    #pragma unroll
    for (int i = 0; i < 4; ++i) {
        agp[i] = Wp + (size_t)(co0 + s_rb + i * 32) * 512 + s_col;
        bgp[i] = Ot + (size_t)(s0  + s_rb + i * 32) * 512 + s_col;
    }

    const int wm = (w4 & 1) * 64;
    const int wn = (w4 >> 1) * 64;
    const int fr = lane & 15;
    const int qd = lane >> 4;
    int arow[4], brow[4];
    #pragma unroll
    for (int i = 0; i < 4; ++i) {
        arow[i] = wm + i * 16 + fr;
        brow[i] = wn + i * 16 + fr;
    }

    f32x4 acc[4][4] = {};

    auto stage = [&](int it, int slot) {
        const int kb = it * 64;
        #pragma unroll
        for (int i = 0; i < 4; ++i) {
            gl_lds16(agp[i] + kb, &A_lds[slot][i * 2048 + w4 * 512]);
            gl_lds16(bgp[i] + kb, &B_lds[slot][i * 2048 + w4 * 512]);
        }
    };

    // prologue: 2 K-tiles in flight (16 loads/thread outstanding)
    stage(0, 0);
    stage(1, 1);

    for (int it = 0; it < 8; ++it) {
        const int s = it & 1;
        // stage(it)'s 8 loads landed; stage(it+1)'s 8 stay in flight
        asm volatile("s_waitcnt vmcnt(8)" ::: "memory");
        asm volatile("s_barrier" ::: "memory");

        const u16* Ab = &A_lds[s][0];
        const u16* Bb = &B_lds[s][0];
        short8 af[2][4], bq[2][4];
        #pragma unroll
        for (int ks = 0; ks < 2; ++ks) {
            #pragma unroll
            for (int i = 0; i < 4; ++i) {
                int c = (ks * 4 + qd) ^ (arow[i] & 7);
                af[ks][i] = *(const short8*)&Ab[arow[i] * 64 + c * 8];
            }
            #pragma unroll
            for (int jn = 0; jn < 4; ++jn) {
                int c = (ks * 4 + qd) ^ (brow[jn] & 7);
                bq[ks][jn] = *(const short8*)&Bb[brow[jn] * 64 + c * 8];
            }
        }

        // all my ds_reads of slot s are issued-and-counted; after the
        // barrier every wave's are complete -> slot s may be rewritten
        asm volatile("s_waitcnt lgkmcnt(0)" ::: "memory");
        asm volatile("s_barrier" ::: "memory");

        int itn = it + 2; if (itn >= 8) itn -= 8;   // wrap = harmless dummy
        stage(itn, s);

        __builtin_amdgcn_s_setprio(1);
        #pragma unroll
        for (int ks = 0; ks < 2; ++ks)
            #pragma unroll
            for (int i = 0; i < 4; ++i)
                #pragma unroll
                for (int jn = 0; jn < 4; ++jn)
                    acc[i][jn] = __builtin_amdgcn_mfma_f32_16x16x32_bf16(
                        af[ks][i], bq[ks][jn], acc[i][jn], 0, 0, 0);
        __builtin_amdgcn_s_setprio(0);
    }

    const float rwv = *rwp;
    #pragma unroll
    for (int i = 0; i < 4; ++i) {
        int co_b = co0 + wm + i * 16 + qd * 4;
        #pragma unroll
        for (int jn = 0; jn < 4; ++jn) {
            int sp = s0 + wn + jn * 16 + fr;
            #pragma unroll
            for (int r = 0; r < 4; ++r) {
                size_t a = (size_t)(co_b + r) * 1024 + sp;
                outp[a] = xr[a] + rwv * acc[i][jn][r];
            }
        }
    }
}

// ---------------------------------------------------------------------------
extern "C" void kernel_launch(void* const* d_in, const int* in_sizes, int n_in,
                              void* d_out, int out_size, void* d_ws, size_t ws_size,
                              hipStream_t stream) {
    const float* x_l = (const float*)d_in[0];
    const float* x_g = (const float*)d_in[1];
    const float* Wk1 = (const float*)d_in[2];
    const float* Wq1 = (const float*)d_in[3];
    const float* Wv1 = (const float*)d_in[4];
    const float* Wk2 = (const float*)d_in[5];
    const float* Wq2 = (const float*)d_in[6];
    const float* Wv2 = (const float*)d_in[7];
    const float* Wp1 = (const float*)d_in[8];
    const float* Wp2 = (const float*)d_in[9];
    const float* rw  = (const float*)d_in[10];

    u16* ws  = (u16*)d_ws;
    u16* xt  = ws;                       // 9.5 MB
    u16* wbf = ws + XT_ELEMS;            // 28.3 MB
    u16* Kl  = wbf + WB_ELEMS;
    u16* Ql  = Kl  + TSLOT;
    u16* Vtl = Ql  + TSLOT;
    u16* Kg  = Vtl + TSLOT;
    u16* Qg  = Kg  + TSLOT;
    u16* Vtg = Qg  + TSLOT;
    u16* Otg = Vtg + TSLOT;
    u16* Otl = Otg + TSLOT;
    u16* wpb = Otl + TSLOT;              // 1 MB

    float* out0 = (float*)d_out;
    float* out1 = out0 + (size_t)TSLOT;

    prep_all<<<4288, 256, 0, stream>>>(
        x_l, x_g, Wk1, Wq1, Wv1, Wk2, Wq2, Wv2, Wp1, Wp2, xt, wbf, wpb);

    conv_gemm<<<256, 512, 0, stream>>>(
        xt, wbf, Kl, Ql, Vtl, Kg, Qg, Vtg);

    attn_mfma<<<dim3(32, 8, 2), 256, 0, stream>>>(
        Qg, Kl, Vtl, Otg, Ql, Kg, Vtg, Otl);

    proj_mfma<<<dim3(4, 8, 8), 256, 0, stream>>>(
        wpb, Otl, Otg, x_l, x_g, rw, out0, out1);
}

// Round 13
// 258.479 us; speedup vs baseline: 2.4205x; 1.0127x over previous
//
#include <hip/hip_runtime.h>
#include <hip/hip_bf16.h>
#include <stdint.h>

typedef unsigned short u16;
typedef unsigned int u32;

#define TSLOT 2097152              // elements per [4][8][512][128] tensor
#define XT_ELEMS 4734976ull        // 8 x 34 x 34 x 512
#define WB_ELEMS 14155776ull       // 6 x 512 x 4608 (tap-major k')
#define WPB_ELEMS 524288ull        // 2 x 512 x 512

typedef __attribute__((ext_vector_type(8))) short short8;
typedef __attribute__((ext_vector_type(8))) unsigned short u16x8;
typedef __attribute__((ext_vector_type(4))) float f32x4;

__device__ __forceinline__ u16 f2bf(float f) {
    union { u32 i; float f; } v; v.f = f;
    u32 u = v.i;
    return (u16)((u + 0x7FFFu + ((u >> 16) & 1u)) >> 16);  // RNE
}
__device__ __forceinline__ u32 pkbf(float a, float b) {
    __hip_bfloat162 h = __float22bfloat162_rn(make_float2(a, b));
    u32 u; __builtin_memcpy(&u, &h, 4); return u;
}

// async global->LDS, 16B per lane; lds dest is wave-uniform base + lane*16.
// Source address is PER-LANE ARBITRARY (only needs 16B contiguity per lane).
__device__ __forceinline__ void gl_lds16(const u16* g, u16* l) {
    __builtin_amdgcn_global_load_lds(
        (const __attribute__((address_space(1))) void*)(uintptr_t)(const void*)g,
        (__attribute__((address_space(3))) void*)(uintptr_t)(void*)l,
        16, 0, 0);
}

// ---------------------------------------------------------------------------
// prep_all: one launch, three roles.
//  [0,1088):    xt transpose: xt[nimg 8][yy 34][xx 34][ci 512] bf16, zero-pad
//  [1088,4160): conv-weight reorder fp32->bf16 tap-major (r12: coalesced)
//  [4160,4288): proj weights fp32->bf16  wpb[2][512][512]
// ---------------------------------------------------------------------------
__global__ __launch_bounds__(256) void prep_all(
    const float* __restrict__ xl, const float* __restrict__ xg,
    const float* __restrict__ w0, const float* __restrict__ w1,
    const float* __restrict__ w2, const float* __restrict__ w3,
    const float* __restrict__ w4, const float* __restrict__ w5,
    const float* __restrict__ wp1, const float* __restrict__ wp2,
    u16* __restrict__ xt, u16* __restrict__ wbf, u16* __restrict__ wpb)
{
    __shared__ u16 sh[4608];
    const int b = blockIdx.x;
    const int t = threadIdx.x;

    if (b < 1088) {
        const int nimg = b / 136;
        const int rem  = b - nimg * 136;
        const int yy   = rem >> 2;
        const int cig  = rem & 3;
        const int img  = nimg >> 2, n = nimg & 3;
        const float* srcx = (img ? xg : xl);
        u16* ob = xt + (((size_t)nimg * 34 + yy) * 34) * 512 + cig * 128;

        u16 (*xls)[132] = (u16(*)[132])sh;   // [xx 32][ci 128]
        const bool interior = (yy >= 1 && yy <= 32);
        if (interior) {
            for (int v = t; v < 4096; v += 256) {
                int ci_l = v >> 5, xx0 = v & 31;
                float vv = srcx[(((size_t)n * 512 + cig * 128 + ci_l) * 32 + (yy - 1)) * 32 + xx0];
                xls[xx0][ci_l] = f2bf(vv);
            }
            __syncthreads();
        }
        for (int v = t; v < 544; v += 256) {
            int xx = v >> 4, l16 = v & 15;
            u16x8 st;
            if (interior && xx >= 1 && xx <= 32) {
                #pragma unroll
                for (int j = 0; j < 8; ++j) st[j] = xls[xx - 1][l16 * 8 + j];
            } else {
                #pragma unroll
                for (int j = 0; j < 8; ++j) st[j] = 0;
            }
            *(u16x8*)(ob + (size_t)xx * 512 + l16 * 8) = st;
        }
        return;
    }
    if (b < 4160) {
        const int idx = b - 1088;
        const int wt = idx >> 9, co = idx & 511;
        const float* srcw = wt == 0 ? w0 : wt == 1 ? w1 : wt == 2 ? w2
                          : wt == 3 ? w3 : wt == 4 ? w4 : w5;
        const float* wr = srcw + (size_t)co * 4608;
        for (int k = t; k < 4608; k += 256)
            sh[k] = f2bf(wr[k]);                 // sh[k = ci*9+tap]
        __syncthreads();
        u16* orow = wbf + ((size_t)wt * 512 + co) * 4608;
        for (int v = t; v < 4608; v += 256) {
            int tap = v >> 9, ci = v & 511;
            orow[v] = sh[ci * 9 + tap];              // k' = tap*512+ci
        }
        return;
    }
    const int b3 = b - 4160;
    const float* src = (b3 < 64) ? wp1 : wp2;
    const size_t base = (size_t)(b3 & 63) * 4096 + t * 16;
    u16* dst = wpb + ((b3 < 64) ? 0 : 262144) + base;
    const float4* s4 = (const float4*)(src + base);
    float4 f0 = s4[0], f1 = s4[1], f2 = s4[2], f3 = s4[3];
    u32 p[4];
    p[0] = pkbf(f0.x, f0.y); p[1] = pkbf(f0.z, f0.w);
    p[2] = pkbf(f1.x, f1.y); p[3] = pkbf(f1.z, f1.w);
    *(uint4*)dst = *(uint4*)p;
    p[0] = pkbf(f2.x, f2.y); p[1] = pkbf(f2.z, f2.w);
    p[2] = pkbf(f3.x, f3.y); p[3] = pkbf(f3.z, f3.w);
    *(uint4*)(dst + 8) = *(uint4*)p;
}

// ---------------------------------------------------------------------------
// Conv GEMM v13: ONE barrier per K-tile (distance-1 prefetch, 2 slots).
//  v7 had 2 rendezvous/K-tile; the mid-barrier guarded stage(kt+2) into the
//  slot being read THIS iteration. v13 stages kt+1 into slot s^1, which was
//  last read at kt-1 and provably consumed (compiler inserts lgkmcnt before
//  MFMA operand use) before any wave crossed this iteration's top barrier
//  -> WAR-safe with NO mid-barrier, NO lgkm drain. Top wait is vmcnt(0)
//  but stage(kt+1) was issued before ~1900 cyc of MFMA -> covered.
//  Waves may de-phase within the K-tile -> cross-wave LDS||MFMA overlap
//  (m114). Read/accumulate order unchanged -> bit-identical output.
//  (History: v8 119, v9 107, v10 210, v11 481, v12 197 — all ADDED sync or
//  changed operand path; this is the first that REMOVES a barrier.)
// ---------------------------------------------------------------------------
__global__ __launch_bounds__(512, 2) void conv_gemm(
    const u16* __restrict__ xt, const u16* __restrict__ wbf,
    u16* __restrict__ kl, u16* __restrict__ ql, u16* __restrict__ vl,
    u16* __restrict__ kg, u16* __restrict__ qg, u16* __restrict__ vg)
{
    __shared__ __align__(16) u16 A_lds[2][16384];   // [slot][256 rows x 64]
    __shared__ __align__(16) u16 B_lds[2][12288];   // [slot][192 rows x 64]

    const int t    = threadIdx.x;        // 0..511
    const int lane = t & 63;
    const int w    = t >> 6;             // 0..7

    // 2D XCD swizzle: XCD (bid&7) -> (mt-group, nt-group) = (x>>1, x&1)
    const int bid = blockIdx.x;          // 0..255
    const int x   = bid & 7;
    const int j   = bid >> 3;            // 0..31
    const int mt  = (x >> 1) * 8 + (j >> 2);   // 0..31
    const int nt  = (x & 1) * 4 + (j & 3);     // 0..7

    const int m0   = mt * 256;
    const int nimg = m0 >> 10;           // constant per tile
    const int img  = nimg >> 2;
    const int y0   = (m0 & 1023) >> 5;
    const int n0   = nt * 192;           // absolute col in [0,1536)

    const int l8    = lane >> 3;
    const int scol8 = ((lane & 7) ^ l8) * 8;   // pre-swizzled source chunk

    const u16* agp[4];
    const u16* bgp[3];
    #pragma unroll
    for (int i = 0; i < 4; ++i) {
        const int ra = i * 64 + w * 8 + l8;
        const int yy = y0 + (ra >> 5);
        const int xx = ra & 31;
        agp[i] = xt + (((size_t)nimg * 34 + yy) * 34 + xx) * 512 + scol8;
    }
    #pragma unroll
    for (int i = 0; i < 3; ++i) {
        const int ra = i * 64 + w * 8 + l8;
        bgp[i] = wbf + ((size_t)img * 1536 + n0 + ra) * 4608 + scol8;
    }

    const int fr  = lane & 15;
    const int qd  = lane >> 4;
    const int wm  = (w & 3) * 64;        // wave M offset (4-way, 64 rows)
    const int wn  = (w >> 2) * 96;       // wave N offset (2-way, 96 cols)
    const int cxa = fr & 7;

    f32x4 acc[4][6] = {};

    auto stageA = [&](int kt, int slot) {
        const int tap = kt >> 3, cb = kt & 7;
        const int ky = tap / 3, kx = tap - ky * 3;
        const int toff = (ky * 34 + kx) * 512 + cb * 64;
        #pragma unroll
        for (int i = 0; i < 4; ++i)
            gl_lds16(agp[i] + toff, &A_lds[slot][i * 4096 + w * 512]);
    };
    auto stageB = [&](int kt, int slot) {
        #pragma unroll
        for (int i = 0; i < 3; ++i)
            gl_lds16(bgp[i] + kt * 64, &B_lds[slot][i * 4096 + w * 512]);
    };

    // prologue: stage(0) only (7 loads/thread in flight)
    stageA(0, 0); stageB(0, 0);

    for (int kt = 0; kt < 72; ++kt) {
        const int s = kt & 1;
        // stage(kt) landed (issued ~1 full MFMA block ago, covered wait)
        asm volatile("s_waitcnt vmcnt(0)" ::: "memory");
        asm volatile("s_barrier" ::: "memory");

        const u16* Ab = &A_lds[s][0];
        const u16* Bb = &B_lds[s][0];

        // all fragment reads for this K-tile
        short8 af[4][2], bqA[3][2], bqB[3][2];
        #pragma unroll
        for (int mi = 0; mi < 4; ++mi)
            #pragma unroll
            for (int ks = 0; ks < 2; ++ks)
                af[mi][ks] = *(const short8*)&Ab[(wm + mi * 16 + fr) * 64
                                                 + (((ks * 4 + qd) ^ cxa) * 8)];
        #pragma unroll
        for (int nj = 0; nj < 3; ++nj)
            #pragma unroll
            for (int ks = 0; ks < 2; ++ks)
                bqA[nj][ks] = *(const short8*)&Bb[(wn + nj * 16 + fr) * 64
                                                  + (((ks * 4 + qd) ^ cxa) * 8)];
        #pragma unroll
        for (int nj = 0; nj < 3; ++nj)
            #pragma unroll
            for (int ks = 0; ks < 2; ++ks)
                bqB[nj][ks] = *(const short8*)&Bb[(wn + 48 + nj * 16 + fr) * 64
                                                  + (((ks * 4 + qd) ^ cxa) * 8)];

        // prefetch kt+1 into slot s^1. WAR-safe without a barrier: slot s^1
        // was last read at kt-1, and those reads were consumed by kt-1's
        // MFMAs (auto-lgkmcnt) before every wave crossed the barrier above.
        int ktn = kt + 1; if (ktn >= 72) ktn = 0;   // wrap = harmless dummy
        stageA(ktn, s ^ 1);
        stageB(ktn, s ^ 1);

        // cluster 1: 4m x 3n x 2ks = 24 MFMA
        __builtin_amdgcn_s_setprio(1);
        #pragma unroll
        for (int ks = 0; ks < 2; ++ks)
            #pragma unroll
            for (int mi = 0; mi < 4; ++mi)
                #pragma unroll
                for (int nj = 0; nj < 3; ++nj)
                    acc[mi][nj] = __builtin_amdgcn_mfma_f32_16x16x32_bf16(
                        af[mi][ks], bqA[nj][ks], acc[mi][nj], 0, 0, 0);
        __builtin_amdgcn_s_setprio(0);

        // cluster 2: 2m x 3n x 2ks = 12 MFMA
        __builtin_amdgcn_s_setprio(1);
        #pragma unroll
        for (int ks = 0; ks < 2; ++ks)
            #pragma unroll
            for (int mi = 0; mi < 2; ++mi)
                #pragma unroll
                for (int nj = 0; nj < 3; ++nj)
                    acc[mi][3 + nj] = __builtin_amdgcn_mfma_f32_16x16x32_bf16(
                        af[mi][ks], bqB[nj][ks], acc[mi][3 + nj], 0, 0, 0);
        __builtin_amdgcn_s_setprio(0);

        // cluster 3: 2m x 3n x 2ks = 12 MFMA
        __builtin_amdgcn_s_setprio(1);
        #pragma unroll
        for (int ks = 0; ks < 2; ++ks)
            #pragma unroll
            for (int mi = 2; mi < 4; ++mi)
                #pragma unroll
                for (int nj = 0; nj < 3; ++nj)
                    acc[mi][3 + nj] = __builtin_amdgcn_mfma_f32_16x16x32_bf16(
                        af[mi][ks], bqB[nj][ks], acc[mi][3 + nj], 0, 0, 0);
        __builtin_amdgcn_s_setprio(0);
    }

    // epilogue: rows m = m0 + wm + i*16 + qd*4 + r
    //           cols (absolute) = n0 + wn + j*16 + fr  -> (wtj, co) per frag
    const int m_in = m0 & 4095;
    const int n_i  = m_in >> 10;
    const int sp0  = m_in & 1023;
    #pragma unroll
    for (int i = 0; i < 4; ++i) {
        const int mrow = wm + i * 16;
        const int head = (sp0 + mrow) >> 7;
        const int dd0  = (mrow & 127) + qd * 4;
        const size_t hoff = (size_t)(n_i * 8 + head) * 65536;
        #pragma unroll
        for (int jn = 0; jn < 6; ++jn) {
            const int co_abs = n0 + wn + jn * 16 + fr;
            const int wtj = co_abs >> 9;          // wave-uniform
            const int co  = co_abs & 511;
            u16* osel = img == 0 ? (wtj == 0 ? kl : wtj == 1 ? ql : vl)
                                 : (wtj == 0 ? kg : wtj == 1 ? qg : vg);
            u16* ob = osel + hoff;
            if (wtj == 2) {
                // V transposed: [dd][co]
                #pragma unroll
                for (int r = 0; r < 4; ++r)
                    ob[(size_t)(dd0 + r) * 512 + co] = f2bf(acc[i][jn][r]);
            } else {
                ushort4 st;
                st.x = f2bf(acc[i][jn][0]); st.y = f2bf(acc[i][jn][1]);
                st.z = f2bf(acc[i][jn][2]); st.w = f2bf(acc[i][jn][3]);
                *(ushort4*)(ob + (size_t)co * 128 + dd0) = st;
            }
        }
    }
}

// ---------------------------------------------------------------------------
// MFMA flash attention v3 + XCD-local K/V (verified r6: total 261.7).
// r11 NOTE: double-buffered K/V staging REGRESSED — K/V is L2-resident
// per-XCD; extra WAR barriers cost more than the DMA latency they hid.
// ---------------------------------------------------------------------------
__global__ __launch_bounds__(256) void attn_mfma(
    const u16* __restrict__ Q0, const u16* __restrict__ K0,
    const u16* __restrict__ V0, u16* __restrict__ O0,
    const u16* __restrict__ Q1, const u16* __restrict__ K1,
    const u16* __restrict__ V1, u16* __restrict__ O1)
{
    __shared__ __align__(16) u16 Klo[64 * 64];
    __shared__ __align__(16) u16 Khi[64 * 64];
    __shared__ __align__(16) u16 Vs[128 * 64];
    __shared__ u16 Ps[64][72];

    const int t    = threadIdx.x;
    const int lane = t & 63;
    const int w    = t >> 6;
    const int nh   = blockIdx.x;   // head fastest -> same XCD shares K/V
    const int qt   = blockIdx.y;
    const int z    = blockIdx.z;

    const u16* Q = (z ? Q1 : Q0) + (size_t)nh * 65536;
    const u16* K = (z ? K1 : K0) + (size_t)nh * 65536;
    const u16* V = (z ? V1 : V0) + (size_t)nh * 65536;
    u16*       O = (z ? O1 : O0) + (size_t)nh * 65536;

    const int q0    = qt * 64;
    const int s_rb  = w * 8 + (lane >> 3);
    const int s_col = ((lane & 7) ^ (lane >> 3)) * 8;
    u16* const dKl = Klo + w * 512;
    u16* const dKh = Khi + w * 512;
    u16* const dV  = Vs  + w * 512;

    const int fr  = lane & 15;
    const int qd  = lane >> 4;
    const int koq = qd * 8;

    #pragma unroll
    for (int i = 0; i < 2; ++i) {
        const u16* qr = Q + (size_t)(q0 + s_rb + i * 32) * 128;
        gl_lds16(qr + s_col,      dKl + i * 2048);
        gl_lds16(qr + 64 + s_col, dKh + i * 2048);
    }
    __syncthreads();
    short8 aq[4];
    #pragma unroll
    for (int dstep = 0; dstep < 4; ++dstep) {
        const u16* Qh = (dstep < 2) ? Klo : Khi;
        const int cq = (((dstep & 1) * 4 + qd) ^ (fr & 7)) * 8;
        aq[dstep] = *(const short8*)&Qh[(w * 16 + fr) * 64 + cq];
    }

    float m_run[4] = {-3e38f, -3e38f, -3e38f, -3e38f};
    float l_run[4] = {0.f, 0.f, 0.f, 0.f};
    f32x4 Ot[8] = {};
    const float scale = 0.08838834764831845f;

    for (int cb = 0; cb < 8; ++cb) {
        __syncthreads();
        const int kb = cb * 64;
        #pragma unroll
        for (int i = 0; i < 2; ++i) {
            const u16* kr = K + (size_t)(kb + s_rb + i * 32) * 128;
            gl_lds16(kr + s_col,      dKl + i * 2048);
            gl_lds16(kr + 64 + s_col, dKh + i * 2048);
        }
        #pragma unroll
        for (int i = 0; i < 4; ++i)
            gl_lds16(V + (size_t)(s_rb + i * 32) * 512 + kb + s_col, dV + i * 2048);
        __syncthreads();

        f32x4 s[4] = {};
        #pragma unroll
        for (int dstep = 0; dstep < 4; ++dstep) {
            const u16* Kh = (dstep < 2) ? Klo : Khi;
            const int cq = (((dstep & 1) * 4 + qd) ^ (fr & 7)) * 8;
            #pragma unroll
            for (int nj = 0; nj < 4; ++nj) {
                short8 bkf = *(const short8*)&Kh[(nj * 16 + fr) * 64 + cq];
                s[nj] = __builtin_amdgcn_mfma_f32_16x16x32_bf16(aq[dstep], bkf, s[nj], 0, 0, 0);
            }
        }

        float al[4];
        #pragma unroll
        for (int r = 0; r < 4; ++r) {
            float mc = fmaxf(fmaxf(s[0][r], s[1][r]), fmaxf(s[2][r], s[3][r])) * scale;
            mc = fmaxf(mc, __shfl_xor(mc, 1));
            mc = fmaxf(mc, __shfl_xor(mc, 2));
            mc = fmaxf(mc, __shfl_xor(mc, 4));
            mc = fmaxf(mc, __shfl_xor(mc, 8));
            float mn = fmaxf(m_run[r], mc);
            al[r] = __expf(m_run[r] - mn);
            m_run[r] = mn;
            float rs = 0.f;
            #pragma unroll
            for (int nj = 0; nj < 4; ++nj) {
                float p = __expf(s[nj][r] * scale - mn);
                s[nj][r] = p;
                rs += p;
            }
            rs += __shfl_xor(rs, 1);
            rs += __shfl_xor(rs, 2);
            rs += __shfl_xor(rs, 4);
            rs += __shfl_xor(rs, 8);
            l_run[r] = l_run[r] * al[r] + rs;
        }

        #pragma unroll
        for (int nj = 0; nj < 4; ++nj)
            #pragma unroll
            for (int r = 0; r < 4; ++r)
                Ps[w * 16 + qd * 4 + r][nj * 16 + fr] = f2bf(s[nj][r]);

        {
            int srcl = (fr >> 2) << 4;
            float a0 = __shfl(al[0], srcl), a1 = __shfl(al[1], srcl);
            float a2 = __shfl(al[2], srcl), a3 = __shfl(al[3], srcl);
            int rsel = fr & 3;
            float ac = rsel == 0 ? a0 : rsel == 1 ? a1 : rsel == 2 ? a2 : a3;
            #pragma unroll
            for (int t8 = 0; t8 < 8; ++t8)
                #pragma unroll
                for (int r = 0; r < 4; ++r)
                    Ot[t8][r] *= ac;
        }

        #pragma unroll
        for (int ks = 0; ks < 2; ++ks) {
            short8 b = *(const short8*)&Ps[w * 16 + fr][ks * 32 + koq];
            #pragma unroll
            for (int t8 = 0; t8 < 8; ++t8) {
                const int cv = ((ks * 4 + qd) ^ (fr & 7)) * 8;
                short8 a = *(const short8*)&Vs[(t8 * 16 + fr) * 64 + cv];
                Ot[t8] = __builtin_amdgcn_mfma_f32_16x16x32_bf16(a, b, Ot[t8], 0, 0, 0);
            }
        }
    }

    int srcl = (fr >> 2) << 4;
    float l0 = __shfl(l_run[0], srcl), l1 = __shfl(l_run[1], srcl);
    float l2 = __shfl(l_run[2], srcl), l3 = __shfl(l_run[3], srcl);
    int rsel = fr & 3;
    float lc = rsel == 0 ? l0 : rsel == 1 ? l1 : rsel == 2 ? l2 : l3;
    float linv = 1.0f / lc;
    int c = q0 + w * 16 + fr;
    #pragma unroll
    for (int t8 = 0; t8 < 8; ++t8)
        #pragma unroll
        for (int r = 0; r < 4; ++r) {
            int d = t8 * 16 + qd * 4 + r;
            O[(size_t)d * 512 + c] = f2bf(Ot[t8][r] * linv);
        }
}

// ---------------------------------------------------------------------------
// Projection GEMM + residual v2 (verified r12): 2-deep counted-vmcnt pipeline.
// ---------------------------------------------------------------------------
__global__ __launch_bounds__(256) void proj_mfma(
    const u16* __restrict__ wpb,
    const u16* __restrict__ Otl, const u16* __restrict__ Otg,
    const float* __restrict__ x_l, const float* __restrict__ x_g,
    const float* __restrict__ rwp,
    float* __restrict__ out0, float* __restrict__ out1)
{
    __shared__ __align__(16) u16 A_lds[2][128 * 64];
    __shared__ __align__(16) u16 B_lds[2][128 * 64];

    const int t  = threadIdx.x;
    const int ct = blockIdx.x;
    const int st = blockIdx.y;
    const int z  = blockIdx.z;
    const int which = z >> 2;
    const int nn    = z & 3;

    const u16*   Wp = wpb + (which ? 262144 : 0);
    const u16*   Ot = (which ? Otg : Otl) + (size_t)nn * 524288;
    const float* xr = (which ? x_g : x_l) + (size_t)nn * 524288;
    float*     outp = (which ? out1 : out0) + (size_t)nn * 524288;

    const int co0 = ct * 128, s0 = st * 128;
    const int lane = t & 63;
    const int w4   = t >> 6;

    const int s_rb  = w4 * 8 + (lane >> 3);
    const int s_col = ((lane & 7) ^ (lane >> 3)) * 8;
    const u16* agp[4];
    const u16* bgp[4];
    #pragma unroll
    for (int i = 0; i < 4; ++i) {
        agp[i] = Wp + (size_t)(co0 + s_rb + i * 32) * 512 + s_col;
        bgp[i] = Ot + (size_t)(s0  + s_rb + i * 32) * 512 + s_col;
    }

    const int wm = (w4 & 1) * 64;
    const int wn = (w4 >> 1) * 64;
    const int fr = lane & 15;
    const int qd = lane >> 4;
    int arow[4], brow[4];
    #pragma unroll
    for (int i = 0; i < 4; ++i) {
        arow[i] = wm + i * 16 + fr;
        brow[i] = wn + i * 16 + fr;
    }

    f32x4 acc[4][4] = {};

    auto stage = [&](int it, int slot) {
        const int kb = it * 64;
        #pragma unroll
        for (int i = 0; i < 4; ++i) {
            gl_lds16(agp[i] + kb, &A_lds[slot][i * 2048 + w4 * 512]);
            gl_lds16(bgp[i] + kb, &B_lds[slot][i * 2048 + w4 * 512]);
        }
    };

    // prologue: 2 K-tiles in flight (16 loads/thread outstanding)
    stage(0, 0);
    stage(1, 1);

    for (int it = 0; it < 8; ++it) {
        const int s = it & 1;
        // stage(it)'s 8 loads landed; stage(it+1)'s 8 stay in flight
        asm volatile("s_waitcnt vmcnt(8)" ::: "memory");
        asm volatile("s_barrier" ::: "memory");

        const u16* Ab = &A_lds[s][0];
        const u16* Bb = &B_lds[s][0];
        short8 af[2][4], bq[2][4];
        #pragma unroll
        for (int ks = 0; ks < 2; ++ks) {
            #pragma unroll
            for (int i = 0; i < 4; ++i) {
                int c = (ks * 4 + qd) ^ (arow[i] & 7);
                af[ks][i] = *(const short8*)&Ab[arow[i] * 64 + c * 8];
            }
            #pragma unroll
            for (int jn = 0; jn < 4; ++jn) {
                int c = (ks * 4 + qd) ^ (brow[jn] & 7);
                bq[ks][jn] = *(const short8*)&Bb[brow[jn] * 64 + c * 8];
            }
        }

        // all my ds_reads of slot s are issued-and-counted; after the
        // barrier every wave's are complete -> slot s may be rewritten
        asm volatile("s_waitcnt lgkmcnt(0)" ::: "memory");
        asm volatile("s_barrier" ::: "memory");

        int itn = it + 2; if (itn >= 8) itn -= 8;   // wrap = harmless dummy
        stage(itn, s);

        __builtin_amdgcn_s_setprio(1);
        #pragma unroll
        for (int ks = 0; ks < 2; ++ks)
            #pragma unroll
            for (int i = 0; i < 4; ++i)
                #pragma unroll
                for (int jn = 0; jn < 4; ++jn)
                    acc[i][jn] = __builtin_amdgcn_mfma_f32_16x16x32_bf16(
                        af[ks][i], bq[ks][jn], acc[i][jn], 0, 0, 0);
        __builtin_amdgcn_s_setprio(0);
    }

    const float rwv = *rwp;
    #pragma unroll
    for (int i = 0; i < 4; ++i) {
        int co_b = co0 + wm + i * 16 + qd * 4;
        #pragma unroll
        for (int jn = 0; jn < 4; ++jn) {
            int sp = s0 + wn + jn * 16 + fr;
            #pragma unroll
            for (int r = 0; r < 4; ++r) {
                size_t a = (size_t)(co_b + r) * 1024 + sp;
                outp[a] = xr[a] + rwv * acc[i][jn][r];
            }
        }
    }
}

// ---------------------------------------------------------------------------
extern "C" void kernel_launch(void* const* d_in, const int* in_sizes, int n_in,
                              void* d_out, int out_size, void* d_ws, size_t ws_size,
                              hipStream_t stream) {
    const float* x_l = (const float*)d_in[0];
    const float* x_g = (const float*)d_in[1];
    const float* Wk1 = (const float*)d_in[2];
    const float* Wq1 = (const float*)d_in[3];
    const float* Wv1 = (const float*)d_in[4];
    const float* Wk2 = (const float*)d_in[5];
    const float* Wq2 = (const float*)d_in[6];
    const float* Wv2 = (const float*)d_in[7];
    const float* Wp1 = (const float*)d_in[8];
    const float* Wp2 = (const float*)d_in[9];
    const float* rw  = (const float*)d_in[10];

    u16* ws  = (u16*)d_ws;
    u16* xt  = ws;                       // 9.5 MB
    u16* wbf = ws + XT_ELEMS;            // 28.3 MB
    u16* Kl  = wbf + WB_ELEMS;
    u16* Ql  = Kl  + TSLOT;
    u16* Vtl = Ql  + TSLOT;
    u16* Kg  = Vtl + TSLOT;
    u16* Qg  = Kg  + TSLOT;
    u16* Vtg = Qg  + TSLOT;
    u16* Otg = Vtg + TSLOT;
    u16* Otl = Otg + TSLOT;
    u16* wpb = Otl + TSLOT;              // 1 MB

    float* out0 = (float*)d_out;
    float* out1 = out0 + (size_t)TSLOT;

    prep_all<<<4288, 256, 0, stream>>>(
        x_l, x_g, Wk1, Wq1, Wv1, Wk2, Wq2, Wv2, Wp1, Wp2, xt, wbf, wpb);

    conv_gemm<<<256, 512, 0, stream>>>(
        xt, wbf, Kl, Ql, Vtl, Kg, Qg, Vtg);

    attn_mfma<<<dim3(32, 8, 2), 256, 0, stream>>>(
        Qg, Kl, Vtl, Otg, Ql, Kg, Vtg, Otl);

    proj_mfma<<<dim3(4, 8, 8), 256, 0, stream>>>(
        wpb, Otl, Otg, x_l, x_g, rw, out0, out1);
}